// Round 1
// baseline (1480.079 us; speedup 1.0000x reference)
//
#include <hip/hip_runtime.h>
#include <math.h>

// Problem constants
#define NB 4
#define C 64
#define CR 32
#define HH 48
#define WW 48
#define HW 2304
#define LTOT 7470
// pyramid level sizes: 48,43,38,33,28 ; pixel counts 2304,1849,1444,1089,784
// l offsets: 0, 2304, 4153, 5597, 6686, (7470)

// workspace float offsets
#define REF1 0          // 4*64*1849 = 473344
#define REF2 473344     // 4*64*1444 = 369664
#define REF3 843008     // 4*64*1089 = 278784
#define REF4 1121792    // 4*64*784  = 200704
#define MB_OFF 1322496  // 4*2304*32 = 294912   queries [n][q][cr]
#define PYR_OFF 1617408 // 4*32*7470 = 956160   keys    [n][cr][l]
#define RAW_OFF 2573568 // 4*7470*64 = 1912320  values  [n][l][c]
#define YP_OFF 4485888  // 4 quarters * 4*2304*64 = 2359296 (unnormalized partial Y)
#define MP_OFF 6845184  // 4*4*2304 = 36864 (running max)
#define LP_OFF 6882048  // 4*4*2304 = 36864 (running denom)
// total = 6918912 floats = 27.7 MB

#define LQ 1868  // L quarter size (last = 1866)

__device__ __forceinline__ float cubicw(float d) {
  // torch-style bicubic kernel, a=-0.75
  float ad = fabsf(d);
  float w1 = (1.25f * ad - 2.25f) * ad * ad + 1.0f;
  float w2 = ((-0.75f * ad + 3.75f) * ad - 6.0f) * ad + 3.0f;
  return ad <= 1.0f ? w1 : (ad < 2.0f ? w2 : 0.0f);
}

// ---------------- bicubic resize (scales 0.9,0.8,0.7,0.6) ----------------
__global__ void k_resize(const float* __restrict__ x, float* __restrict__ ws) {
  int tid = blockIdx.x * 256 + threadIdx.x;
  int D, rem;
  if (tid < 473344)       { D = 43; rem = tid; }
  else if (tid < 843008)  { D = 38; rem = tid - 473344; }
  else if (tid < 1121792) { D = 33; rem = tid - 843008; }
  else                    { D = 28; rem = tid - 1121792; }
  int DD = D * D;
  int pix = rem % DD, nc = rem / DD;          // nc = n*64+c
  int py = pix / D, px = pix % D;
  float scale = 48.0f / (float)D;
  float sy = ((float)py + 0.5f) * scale - 0.5f;
  float sx = ((float)px + 0.5f) * scale - 0.5f;
  float y0f = floorf(sy), x0f = floorf(sx);
  int y0 = (int)y0f, x0 = (int)x0f;
  float ty = sy - y0f, tx = sx - x0f;
  float wy[4], wxv[4];
#pragma unroll
  for (int k = 0; k < 4; k++) {
    wy[k]  = cubicw(ty - (float)(k - 1));
    wxv[k] = cubicw(tx - (float)(k - 1));
  }
  const float* src = x + nc * HW;
  float acc = 0.f;
#pragma unroll
  for (int dy = 0; dy < 4; ++dy) {
    int iy = min(max(y0 - 1 + dy, 0), 47);   // border replicate
    const float* row = src + iy * 48;
    float a = 0.f;
#pragma unroll
    for (int dx = 0; dx < 4; ++dx) {
      int ix = min(max(x0 - 1 + dx, 0), 47);
      a = fmaf(wxv[dx], row[ix], a);
    }
    acc = fmaf(wy[dy], a, acc);
  }
  ws[tid] = acc;  // layout matches REF1..REF4 regions exactly
}

// ---------------- query conv 3x3 64->32, pad 1 (zero) ----------------
__global__ void k_qconv(const float* __restrict__ x, const float* __restrict__ wb,
                        const float* __restrict__ bb, float* __restrict__ mb) {
  int tid = blockIdx.x * 256 + threadIdx.x;
  int cr = tid & 31;
  int t2 = tid >> 5;
  int q = t2 % HW;
  int n = t2 / HW;
  int py = q / 48, px = q % 48;
  float acc = bb[cr];
  const float* xn = x + n * C * HW;
  const float* wc = wb + cr * C * 9;
  for (int ic = 0; ic < C; ++ic) {
    const float* xc = xn + ic * HW;
    const float* wk = wc + ic * 9;
#pragma unroll
    for (int ky = 0; ky < 3; ky++) {
      int iy = py + ky - 1;
      if ((unsigned)iy < 48u) {
        const float* row = xc + iy * 48;
#pragma unroll
        for (int kx = 0; kx < 3; kx++) {
          int ix = px + kx - 1;
          if ((unsigned)ix < 48u) acc = fmaf(wk[ky * 3 + kx], row[ix], acc);
        }
      }
    }
  }
  mb[(n * HW + q) * CR + cr] = acc;  // [n][q][cr]
}

// ---------------- key conv 3x3 64->32 pad 1 over all pyramid levels ----------------
__global__ void k_kconv(const float* __restrict__ x, const float* __restrict__ ws,
                        const float* __restrict__ wm, const float* __restrict__ bm,
                        float* __restrict__ pyr) {
  int tid = blockIdx.x * 256 + threadIdx.x;
  int l = tid % LTOT;
  int t2 = tid / LTOT;
  int cr = t2 & 31;
  int n = t2 >> 5;
  int D, p; const float* src;
  if (l < 2304)      { D = 48; p = l;        src = x + n * C * 2304; }
  else if (l < 4153) { D = 43; p = l - 2304; src = ws + REF1 + n * C * 1849; }
  else if (l < 5597) { D = 38; p = l - 4153; src = ws + REF2 + n * C * 1444; }
  else if (l < 6686) { D = 33; p = l - 5597; src = ws + REF3 + n * C * 1089; }
  else               { D = 28; p = l - 6686; src = ws + REF4 + n * C * 784; }
  int DD = D * D;
  int py = p / D, px = p % D;
  float acc = bm[cr];
  const float* wc = wm + cr * C * 9;
  for (int ic = 0; ic < C; ++ic) {
    const float* xc = src + ic * DD;
    const float* wk = wc + ic * 9;
#pragma unroll
    for (int ky = 0; ky < 3; ky++) {
      int iy = py + ky - 1;
      if ((unsigned)iy < (unsigned)D) {
        const float* row = xc + iy * D;
#pragma unroll
        for (int kx = 0; kx < 3; kx++) {
          int ix = px + kx - 1;
          if ((unsigned)ix < (unsigned)D) acc = fmaf(wk[ky * 3 + kx], row[ix], acc);
        }
      }
    }
  }
  pyr[(n * CR + cr) * LTOT + l] = acc;  // [n][cr][l]
}

// ---------------- value conv 1x1 64->64 over all pyramid levels ----------------
__global__ void k_vconv(const float* __restrict__ x, const float* __restrict__ ws,
                        const float* __restrict__ wa, const float* __restrict__ ba,
                        float* __restrict__ raw) {
  int tid = blockIdx.x * 256 + threadIdx.x;
  int c = tid & 63;
  int t2 = tid >> 6;
  int l = t2 % LTOT;
  int n = t2 / LTOT;
  int DD, p; const float* src;
  if (l < 2304)      { DD = 2304; p = l;        src = x + n * C * 2304; }
  else if (l < 4153) { DD = 1849; p = l - 2304; src = ws + REF1 + n * C * 1849; }
  else if (l < 5597) { DD = 1444; p = l - 4153; src = ws + REF2 + n * C * 1444; }
  else if (l < 6686) { DD = 1089; p = l - 5597; src = ws + REF3 + n * C * 1089; }
  else               { DD = 784;  p = l - 6686; src = ws + REF4 + n * C * 784; }
  float acc = ba[c];
  const float* wc = wa + c * C;
  for (int ic = 0; ic < C; ++ic) acc = fmaf(wc[ic], src[ic * DD + p], acc);
  raw[(n * LTOT + l) * C + c] = acc;  // [n][l][c]
}

// ---------------- flash attention over one L quarter ----------------
// grid: (36 q-tiles, 4 batch, 4 L-quarters), block 256 (4 waves)
// phase1: lane(q1=t>>2, cg=t&3) computes 16 scores (lc=4j+cg), online softmax stats
// phase2: lane(qo=lane>>3, co=lane&7, wave wv) owns q∈{qo+8qi}, c∈[co*8,co*8+8),
//         j range [wv*16, wv*16+16) of chunk; 64 fp32 accumulators/lane.
__global__ __launch_bounds__(256) void k_attn(const float* __restrict__ mb,
    const float* __restrict__ pyr, const float* __restrict__ raw,
    float* __restrict__ Yp, float* __restrict__ mp, float* __restrict__ lp) {
  __shared__ float pyrs[64][36];   // [lc][cr], pad 36: conflict-free f4 reads
  __shared__ float raws[64][64];   // [lc][c]
  __shared__ float P[64][68];      // [q][lc] p-values; reused as Y buffer at end
  __shared__ float A[64];          // per-q alpha for this chunk

  int t = threadIdx.x;
  int qt = blockIdx.x, n = blockIdx.y, quarter = blockIdx.z;
  int q0 = qt * 64;
  int l_begin = quarter * LQ;
  int l_end = min(l_begin + LQ, LTOT);

  int q1 = t >> 2, cg = t & 3;          // phase1 identity
  int lane = t & 63, wv = t >> 6;       // phase2 identity
  int qo = lane >> 3, co = lane & 7;

  const float* mbq = mb + (n * HW + q0 + q1) * CR;
  float qreg[32];
#pragma unroll
  for (int i = 0; i < 32; i++) qreg[i] = mbq[i];

  float m = -INFINITY, lsum = 0.f;
  float yacc[8][8];
#pragma unroll
  for (int qi = 0; qi < 8; qi++)
#pragma unroll
    for (int ci = 0; ci < 8; ci++) yacc[qi][ci] = 0.f;

  const float* pyrn = pyr + n * CR * LTOT;
  const float* rawn = raw + n * LTOT * C;

  for (int l0 = l_begin; l0 < l_end; l0 += 64) {
    // ---- stage K/V chunk ----
#pragma unroll
    for (int k = 0; k < 8; k++) {
      int idx = k * 256 + t;
      int cr = idx >> 6, lc = idx & 63;
      int l = l0 + lc;
      pyrs[lc][cr] = (l < l_end) ? pyrn[cr * LTOT + l] : 0.f;
    }
#pragma unroll
    for (int k = 0; k < 4; k++) {
      int idx = k * 256 + t;            // float4 index into 64x64
      int lc = idx >> 4, c4 = (idx & 15) * 4;
      int l = l0 + lc;
      float4 v = (l < l_end) ? *(const float4*)(rawn + l * C + c4)
                             : make_float4(0.f, 0.f, 0.f, 0.f);
      *(float4*)&raws[lc][c4] = v;
    }
    __syncthreads();

    // ---- phase 1: scores + online softmax stats ----
    float s[16];
#pragma unroll
    for (int j = 0; j < 16; j++) {
      int lc = 4 * j + cg;
      const float4* pc = (const float4*)&pyrs[lc][0];
      float acc = 0.f;
#pragma unroll
      for (int k = 0; k < 8; k++) {
        float4 v = pc[k];
        acc = fmaf(qreg[4 * k + 0], v.x, acc);
        acc = fmaf(qreg[4 * k + 1], v.y, acc);
        acc = fmaf(qreg[4 * k + 2], v.z, acc);
        acc = fmaf(qreg[4 * k + 3], v.w, acc);
      }
      s[j] = (l0 + lc < l_end) ? acc : -INFINITY;
    }
    float cm = s[0];
#pragma unroll
    for (int j = 1; j < 16; j++) cm = fmaxf(cm, s[j]);
    cm = fmaxf(cm, __shfl_xor(cm, 1));
    cm = fmaxf(cm, __shfl_xor(cm, 2));
    float mnew = fmaxf(m, cm);
    float alpha = __expf(m - mnew);   // m=-inf first chunk -> alpha=0
    float ps = 0.f;
#pragma unroll
    for (int j = 0; j < 16; j++) {
      float p = __expf(s[j] - mnew);  // masked -> exp(-inf)=0
      P[q1][4 * j + cg] = p;
      ps += p;
    }
    ps += __shfl_xor(ps, 1);
    ps += __shfl_xor(ps, 2);
    lsum = lsum * alpha + ps;
    m = mnew;
    if (cg == 0) A[q1] = alpha;
    __syncthreads();

    // ---- phase 2: y += P * V (this wave's 16 j's) ----
    float al[8];
#pragma unroll
    for (int qi = 0; qi < 8; qi++) al[qi] = A[qo + 8 * qi];
#pragma unroll
    for (int qi = 0; qi < 8; qi++)
#pragma unroll
      for (int ci = 0; ci < 8; ci++) yacc[qi][ci] *= al[qi];

#pragma unroll
    for (int jg = 0; jg < 4; jg++) {
      int j0 = wv * 16 + jg * 4;
      float4 r0[4], r1[4];
#pragma unroll
      for (int jj = 0; jj < 4; jj++) {
        r0[jj] = *(const float4*)&raws[j0 + jj][co * 8];
        r1[jj] = *(const float4*)&raws[j0 + jj][co * 8 + 4];
      }
#pragma unroll
      for (int qi = 0; qi < 8; qi++) {
        float4 pv = *(const float4*)&P[qo + 8 * qi][j0];
        float pj[4] = {pv.x, pv.y, pv.z, pv.w};
#pragma unroll
        for (int jj = 0; jj < 4; jj++) {
          float p = pj[jj];
          yacc[qi][0] = fmaf(p, r0[jj].x, yacc[qi][0]);
          yacc[qi][1] = fmaf(p, r0[jj].y, yacc[qi][1]);
          yacc[qi][2] = fmaf(p, r0[jj].z, yacc[qi][2]);
          yacc[qi][3] = fmaf(p, r0[jj].w, yacc[qi][3]);
          yacc[qi][4] = fmaf(p, r1[jj].x, yacc[qi][4]);
          yacc[qi][5] = fmaf(p, r1[jj].y, yacc[qi][5]);
          yacc[qi][6] = fmaf(p, r1[jj].z, yacc[qi][6]);
          yacc[qi][7] = fmaf(p, r1[jj].w, yacc[qi][7]);
        }
      }
    }
    __syncthreads();
  }

  // ---- cross-wave reduce (waves held disjoint j partials), reuse P as Y buffer ----
  for (int w = 0; w < 4; ++w) {
    if (wv == w) {
#pragma unroll
      for (int qi = 0; qi < 8; qi++) {
        int q = qo + 8 * qi;
        float* dst = &P[q][co * 8];
        if (w == 0) {
#pragma unroll
          for (int ci = 0; ci < 8; ci++) dst[ci] = yacc[qi][ci];
        } else {
#pragma unroll
          for (int ci = 0; ci < 8; ci++) dst[ci] += yacc[qi][ci];
        }
      }
    }
    __syncthreads();
  }

  // ---- write partials ----
  float* Yout = Yp + ((size_t)(quarter * NB + n) * HW + q0) * C;
#pragma unroll
  for (int k = 0; k < 16; k++) {
    int idx = k * 256 + t;
    int q = idx >> 6, c = idx & 63;
    Yout[q * C + c] = P[q][c];
  }
  if (cg == 0) {
    int base = (quarter * NB + n) * HW + q0 + q1;
    mp[base] = m;
    lp[base] = lsum;
  }
}

// ---------------- combine L-quarter partials + residual ----------------
__global__ void k_combine(const float* __restrict__ x, const float* __restrict__ ws,
                          float* __restrict__ out) {
  int tid = blockIdx.x * 256 + threadIdx.x;
  int c = tid & 63;
  int t2 = tid >> 6;
  int q = t2 % HW;
  int n = t2 / HW;
  const float* Y = ws + YP_OFF;
  const float* mp = ws + MP_OFF;
  const float* lp = ws + LP_OFF;
  int i0 = n * HW + q;
  float m0 = mp[i0], m1 = mp[i0 + NB * HW], m2 = mp[i0 + 2 * NB * HW], m3 = mp[i0 + 3 * NB * HW];
  float mm = fmaxf(fmaxf(m0, m1), fmaxf(m2, m3));
  float e0 = __expf(m0 - mm), e1 = __expf(m1 - mm), e2 = __expf(m2 - mm), e3 = __expf(m3 - mm);
  float denom = lp[i0] * e0 + lp[i0 + NB * HW] * e1 + lp[i0 + 2 * NB * HW] * e2 + lp[i0 + 3 * NB * HW] * e3;
  float num = Y[(size_t)i0 * C + c] * e0
            + Y[((size_t)(i0 + NB * HW)) * C + c] * e1
            + Y[((size_t)(i0 + 2 * NB * HW)) * C + c] * e2
            + Y[((size_t)(i0 + 3 * NB * HW)) * C + c] * e3;
  float y = num / denom;
  int oi = (n * C + c) * HW + q;
  out[oi] = y + x[oi];
}

extern "C" void kernel_launch(void* const* d_in, const int* in_sizes, int n_in,
                              void* d_out, int out_size, void* d_ws, size_t ws_size,
                              hipStream_t stream) {
  const float* x  = (const float*)d_in[0];
  const float* wb = (const float*)d_in[1];
  const float* bb = (const float*)d_in[2];
  const float* wm = (const float*)d_in[3];
  const float* bm = (const float*)d_in[4];
  const float* wa = (const float*)d_in[5];
  const float* ba = (const float*)d_in[6];
  float* out = (float*)d_out;
  float* ws = (float*)d_ws;

  k_resize<<<5166, 256, 0, stream>>>(x, ws);
  k_qconv<<<1152, 256, 0, stream>>>(x, wb, bb, ws + MB_OFF);
  k_kconv<<<3735, 256, 0, stream>>>(x, ws, wm, bm, ws + PYR_OFF);
  k_vconv<<<7470, 256, 0, stream>>>(x, ws, wa, ba, ws + RAW_OFF);
  dim3 g(36, 4, 4);
  k_attn<<<g, 256, 0, stream>>>(ws + MB_OFF, ws + PYR_OFF, ws + RAW_OFF,
                                ws + YP_OFF, ws + MP_OFF, ws + LP_OFF);
  k_combine<<<2304, 256, 0, stream>>>(x, ws, out);
}

// Round 2
// 454.203 us; speedup vs baseline: 3.2586x; 3.2586x over previous
//
#include <hip/hip_runtime.h>
#include <math.h>

typedef unsigned short ushort_t;
typedef __attribute__((ext_vector_type(8))) short short8;
typedef __attribute__((ext_vector_type(4))) float float4v;

// Problem constants
#define NB 4
#define C 64
#define CR 32
#define HW 2304
#define LTOT 7470
#define LPAD 7472   // padded V row stride (16B-aligned rows)
#define NSEG 6
#define SEG 1248    // ceil-ish: 5*1248 + 1230 = 7470

// workspace float offsets
#define REF1 0          // 4*64*1849
#define REF2 473344     // 4*64*1444
#define REF3 843008     // 4*64*1089
#define REF4 1121792    // 4*64*784   (end 1322496)
#define MBBF_F  1322496 // bf16 queries [n][q][cr]        294912 shorts
#define KEYBF_F 1469952 // bf16 keys    [n][l][cr]        956160 shorts
#define RAWTBF_F 1948032// bf16 values^T [n][c][LPAD]     1912832 shorts
#define YP_F   2904448  // fp32 partial Y: NSEG*4*2304*64 = 3538944
#define MP_F   6443392  // NSEG*4*2304
#define LP_F   6498688  // NSEG*4*2304  (end 6553984 floats = 26.2 MB)

static __device__ __forceinline__ ushort_t f2bf(float f) {
  union { float f; unsigned u; } v; v.f = f;
  unsigned r = v.u + 0x7FFF + ((v.u >> 16) & 1);
  return (ushort_t)(r >> 16);
}

__device__ __forceinline__ float cubicw(float d) {
  float ad = fabsf(d);
  float w1 = (1.25f * ad - 2.25f) * ad * ad + 1.0f;
  float w2 = ((-0.75f * ad + 3.75f) * ad - 6.0f) * ad + 3.0f;
  return ad <= 1.0f ? w1 : (ad < 2.0f ? w2 : 0.0f);
}

// ---------------- bicubic resize ----------------
__global__ void k_resize(const float* __restrict__ x, float* __restrict__ ws) {
  int tid = blockIdx.x * 256 + threadIdx.x;
  int D, rem;
  if (tid < 473344)       { D = 43; rem = tid; }
  else if (tid < 843008)  { D = 38; rem = tid - 473344; }
  else if (tid < 1121792) { D = 33; rem = tid - 843008; }
  else                    { D = 28; rem = tid - 1121792; }
  int DD = D * D;
  int pix = rem % DD, nc = rem / DD;
  int py = pix / D, px = pix % D;
  float scale = 48.0f / (float)D;
  float sy = ((float)py + 0.5f) * scale - 0.5f;
  float sx = ((float)px + 0.5f) * scale - 0.5f;
  float y0f = floorf(sy), x0f = floorf(sx);
  int y0 = (int)y0f, x0 = (int)x0f;
  float ty = sy - y0f, tx = sx - x0f;
  float wy[4], wxv[4];
#pragma unroll
  for (int k = 0; k < 4; k++) {
    wy[k]  = cubicw(ty - (float)(k - 1));
    wxv[k] = cubicw(tx - (float)(k - 1));
  }
  const float* src = x + nc * HW;
  float acc = 0.f;
#pragma unroll
  for (int dy = 0; dy < 4; ++dy) {
    int iy = min(max(y0 - 1 + dy, 0), 47);
    const float* row = src + iy * 48;
    float a = 0.f;
#pragma unroll
    for (int dx = 0; dx < 4; ++dx) {
      int ix = min(max(x0 - 1 + dx, 0), 47);
      a = fmaf(wxv[dx], row[ix], a);
    }
    acc = fmaf(wy[dy], a, acc);
  }
  ws[tid] = acc;
}

// ---------------- query conv 3x3 64->32 pad1, block-uniform (n,cr) ----------------
__global__ void k_qconv(const float* __restrict__ x, const float* __restrict__ wb,
                        const float* __restrict__ bb, ushort_t* __restrict__ mbbf) {
  int p = blockIdx.x * 256 + threadIdx.x;
  int n = blockIdx.y >> 5, cr = blockIdx.y & 31;
  int py = p / 48, px = p % 48;
  const float* wc = wb + cr * 576;
  const float* xn = x + n * C * HW;
  float acc = bb[cr];
  for (int ic = 0; ic < C; ++ic) {
    const float* xc = xn + ic * HW;
    const float* wk = wc + ic * 9;
#pragma unroll
    for (int ky = 0; ky < 3; ky++) {
      int iy = py + ky - 1;
      if ((unsigned)iy < 48u) {
        const float* row = xc + iy * 48;
#pragma unroll
        for (int kx = 0; kx < 3; kx++) {
          int ix = px + kx - 1;
          if ((unsigned)ix < 48u) acc = fmaf(wk[ky * 3 + kx], row[ix], acc);
        }
      }
    }
  }
  mbbf[(n * HW + p) * CR + cr] = f2bf(acc);
}

// ---------------- key conv 3x3 64->32 pad1, all levels, block-uniform (n,cr) ----------------
__global__ void k_kconv(const float* __restrict__ x, const float* __restrict__ ws,
                        const float* __restrict__ wm, const float* __restrict__ bm,
                        ushort_t* __restrict__ keybf) {
  int l = blockIdx.x * 256 + threadIdx.x;
  if (l >= LTOT) return;
  int n = blockIdx.y >> 5, cr = blockIdx.y & 31;
  int D, p; const float* src;
  if (l < 2304)      { D = 48; p = l;        src = x + n * C * 2304; }
  else if (l < 4153) { D = 43; p = l - 2304; src = ws + REF1 + n * C * 1849; }
  else if (l < 5597) { D = 38; p = l - 4153; src = ws + REF2 + n * C * 1444; }
  else if (l < 6686) { D = 33; p = l - 5597; src = ws + REF3 + n * C * 1089; }
  else               { D = 28; p = l - 6686; src = ws + REF4 + n * C * 784; }
  int DD = D * D;
  int py = p / D, px = p % D;
  float acc = bm[cr];
  const float* wc = wm + cr * 576;
  for (int ic = 0; ic < C; ++ic) {
    const float* xc = src + ic * DD;
    const float* wk = wc + ic * 9;
#pragma unroll
    for (int ky = 0; ky < 3; ky++) {
      int iy = py + ky - 1;
      if ((unsigned)iy < (unsigned)D) {
        const float* row = xc + iy * D;
#pragma unroll
        for (int kx = 0; kx < 3; kx++) {
          int ix = px + kx - 1;
          if ((unsigned)ix < (unsigned)D) acc = fmaf(wk[ky * 3 + kx], row[ix], acc);
        }
      }
    }
  }
  keybf[((size_t)(n * LTOT + l)) * CR + cr] = f2bf(acc);
}

// ---------------- value conv 1x1 64->64, transposed bf16 out, block-uniform (n,c) ----------------
__global__ void k_vconv(const float* __restrict__ x, const float* __restrict__ ws,
                        const float* __restrict__ wa, const float* __restrict__ ba,
                        ushort_t* __restrict__ rawtbf) {
  int l = blockIdx.x * 256 + threadIdx.x;
  if (l >= LTOT) return;
  int n = blockIdx.y >> 6, c = blockIdx.y & 63;
  int DD, p; const float* src;
  if (l < 2304)      { DD = 2304; p = l;        src = x + n * C * 2304; }
  else if (l < 4153) { DD = 1849; p = l - 2304; src = ws + REF1 + n * C * 1849; }
  else if (l < 5597) { DD = 1444; p = l - 4153; src = ws + REF2 + n * C * 1444; }
  else if (l < 6686) { DD = 1089; p = l - 5597; src = ws + REF3 + n * C * 1089; }
  else               { DD = 784;  p = l - 6686; src = ws + REF4 + n * C * 784; }
  float acc = ba[c];
  const float* wc = wa + c * C;
  for (int ic = 0; ic < C; ++ic) acc = fmaf(wc[ic], src[ic * DD + p], acc);
  rawtbf[((size_t)(n * C + c)) * LPAD + l] = f2bf(acc);
}

// ---------------- MFMA flash attention over one L segment ----------------
// grid (36 q-tiles, 4 batch, NSEG), block 256 = 4 waves. Wave owns 16 q rows.
// Scores: D[q][l] = mfma_16x16x32_bf16(Q-frag, K-frag). Softmax stats in-register
// (C/D row = quad*4+reg). P -> per-wave LDS (bf16, stride 72) -> A-frag for PV.
// K and V^T staged in LDS in frag order (conflict-free b128 reads).
__global__ __launch_bounds__(256) void k_attn(const ushort_t* __restrict__ mb,
    const ushort_t* __restrict__ keyb, const ushort_t* __restrict__ rawt,
    float* __restrict__ Yp, float* __restrict__ mp, float* __restrict__ lp) {
  __shared__ __align__(16) ushort_t KsF[2048];     // 4 l-tiles * 64 lanes * 8
  __shared__ __align__(16) ushort_t VsF[4096];     // 8 (kt,ct) frags * 64 lanes * 8
  __shared__ __align__(16) ushort_t Pl[4 * 1152];  // per-wave P[16][72]

  int t = threadIdx.x;
  int n = blockIdx.y, seg = blockIdx.z;
  int lane = t & 63, wv = t >> 6;
  int col = lane & 15, quad = lane >> 4;
  int qb = blockIdx.x * 64 + wv * 16;
  int l_begin = seg * SEG;
  int l_end = min(l_begin + SEG, LTOT);

  // Q A-fragment: A[m=col][k=quad*8+j]
  short8 qA = *(const short8*)(mb + ((size_t)(n * HW + qb + col)) * CR + quad * 8);

  float4v Y[4];
#pragma unroll
  for (int ct = 0; ct < 4; ct++)
#pragma unroll
    for (int r = 0; r < 4; r++) Y[ct][r] = 0.f;
  float m[4], ls[4];
#pragma unroll
  for (int r = 0; r < 4; r++) { m[r] = -INFINITY; ls[r] = 0.f; }

  ushort_t* Pw = Pl + wv * 1152;
  const ushort_t* keyn = keyb + (size_t)n * LTOT * CR;
  const ushort_t* rawn = rawt + (size_t)n * C * LPAD;
  const float4v zero4 = {0.f, 0.f, 0.f, 0.f};

  // staging addresses (frag-order: dest chunk id == source frag-lane id)
  int kl_off = ((t >> 6) << 4) + (t & 15);      // l within chunk for K staging
  int kg = (t >> 4) & 3;

  for (int l0 = l_begin; l0 < l_end; l0 += 64) {
    // stage K chunk (4 KB): lane chunk t holds K[l=16*tile+col][cr=8g..8g+8]
    *(uint4*)&KsF[t * 8] =
        *(const uint4*)(keyn + ((size_t)(l0 + kl_off)) * CR + kg * 8);
    // stage V^T chunk (8 KB): chunk v holds V[l=kt*32+8g..][c=ct*16+cc]
#pragma unroll
    for (int i = 0; i < 2; i++) {
      int v = t + (i << 8);
      int kt = v >> 8, ct = (v >> 6) & 3, g = (v >> 4) & 3, cc = v & 15;
      *(uint4*)&VsF[v * 8] =
          *(const uint4*)(rawn + ((size_t)(ct * 16 + cc)) * LPAD + l0 + kt * 32 + g * 8);
    }
    __syncthreads();

    // scores: 4 MFMAs, then mask ragged tail
    float sv[4][4];
#pragma unroll
    for (int tt = 0; tt < 4; tt++) {
      short8 bK = *(const short8*)&KsF[(tt * 64 + lane) * 8];
      float4v S = __builtin_amdgcn_mfma_f32_16x16x32_bf16(qA, bK, zero4, 0, 0, 0);
      int lg = l0 + tt * 16 + col;
      bool ok = lg < l_end;
#pragma unroll
      for (int r = 0; r < 4; r++) sv[tt][r] = ok ? S[r] : -INFINITY;
    }

    // row max (rows = quad*4+r live in 16 lanes of same quad)
    float rmax[4];
#pragma unroll
    for (int r = 0; r < 4; r++)
      rmax[r] = fmaxf(fmaxf(sv[0][r], sv[1][r]), fmaxf(sv[2][r], sv[3][r]));
#pragma unroll
    for (int off = 1; off < 16; off <<= 1)
#pragma unroll
      for (int r = 0; r < 4; r++) rmax[r] = fmaxf(rmax[r], __shfl_xor(rmax[r], off));

    float al[4];
#pragma unroll
    for (int r = 0; r < 4; r++) {
      float mn = fmaxf(m[r], rmax[r]);
      al[r] = __expf(m[r] - mn);   // first chunk: exp(-inf)=0
      m[r] = mn;
    }
    float rsum[4] = {0.f, 0.f, 0.f, 0.f};
#pragma unroll
    for (int tt = 0; tt < 4; tt++)
#pragma unroll
      for (int r = 0; r < 4; r++) {
        float p = __expf(sv[tt][r] - m[r]);   // masked -> 0
        rsum[r] += p;
        Pw[(quad * 4 + r) * 72 + tt * 16 + col] = f2bf(p);
      }
#pragma unroll
    for (int off = 1; off < 16; off <<= 1)
#pragma unroll
      for (int r = 0; r < 4; r++) rsum[r] += __shfl_xor(rsum[r], off);
#pragma unroll
    for (int r = 0; r < 4; r++) ls[r] = ls[r] * al[r] + rsum[r];
#pragma unroll
    for (int ct = 0; ct < 4; ct++)
#pragma unroll
      for (int r = 0; r < 4; r++) Y[ct][r] *= al[r];
    __syncthreads();  // P visible wave-wide; also orders vs staging

    // PV: Y[q][c] += P[q][l] V[l][c], two k-tiles of 32
#pragma unroll
    for (int kt = 0; kt < 2; kt++) {
      short8 aP = *(const short8*)&Pw[col * 72 + kt * 32 + quad * 8];
#pragma unroll
      for (int ct = 0; ct < 4; ct++) {
        short8 bV = *(const short8*)&VsF[(((kt << 2) | ct) * 64 + lane) * 8];
        Y[ct] = __builtin_amdgcn_mfma_f32_16x16x32_bf16(aP, bV, Y[ct], 0, 0, 0);
      }
    }
    __syncthreads();  // before next chunk overwrites KsF/VsF
  }

  // write partials (unnormalized) + stats
  float* yo = Yp + ((size_t)(seg * NB + n) * HW + qb) * C;
#pragma unroll
  for (int ct = 0; ct < 4; ct++)
#pragma unroll
    for (int r = 0; r < 4; r++)
      yo[(quad * 4 + r) * C + ct * 16 + col] = Y[ct][r];
  if (col == 0) {
    int base = (seg * NB + n) * HW + qb + quad * 4;
#pragma unroll
    for (int r = 0; r < 4; r++) { mp[base + r] = m[r]; lp[base + r] = ls[r]; }
  }
}

// ---------------- combine segment partials + residual ----------------
__global__ void k_combine(const float* __restrict__ x, const float* __restrict__ ws,
                          float* __restrict__ out) {
  int tid = blockIdx.x * 256 + threadIdx.x;
  int c = tid & 63;
  int t2 = tid >> 6;
  int q = t2 % HW;
  int n = t2 / HW;
  const float* Yv = ws + YP_F;
  const float* mp = ws + MP_F;
  const float* lp = ws + LP_F;
  int i0 = n * HW + q;
  float mm = -INFINITY;
#pragma unroll
  for (int s = 0; s < NSEG; s++) mm = fmaxf(mm, mp[s * NB * HW + i0]);
  float den = 0.f, num = 0.f;
#pragma unroll
  for (int s = 0; s < NSEG; s++) {
    int idx = s * NB * HW + i0;
    float e = __expf(mp[idx] - mm);
    den += lp[idx] * e;
    num += Yv[(size_t)idx * C + c] * e;
  }
  int oi = (n * C + c) * HW + q;
  out[oi] = num / den + x[oi];
}

extern "C" void kernel_launch(void* const* d_in, const int* in_sizes, int n_in,
                              void* d_out, int out_size, void* d_ws, size_t ws_size,
                              hipStream_t stream) {
  const float* x  = (const float*)d_in[0];
  const float* wb = (const float*)d_in[1];
  const float* bb = (const float*)d_in[2];
  const float* wm = (const float*)d_in[3];
  const float* bm = (const float*)d_in[4];
  const float* wa = (const float*)d_in[5];
  const float* ba = (const float*)d_in[6];
  float* out = (float*)d_out;
  float* ws = (float*)d_ws;
  ushort_t* mbbf   = (ushort_t*)(ws + MBBF_F);
  ushort_t* keybf  = (ushort_t*)(ws + KEYBF_F);
  ushort_t* rawtbf = (ushort_t*)(ws + RAWTBF_F);

  k_resize<<<5166, 256, 0, stream>>>(x, ws);
  k_qconv<<<dim3(9, 128), 256, 0, stream>>>(x, wb, bb, mbbf);
  k_kconv<<<dim3(30, 128), 256, 0, stream>>>(x, ws, wm, bm, keybf);
  k_vconv<<<dim3(30, 256), 256, 0, stream>>>(x, ws, wa, ba, rawtbf);
  k_attn<<<dim3(36, 4, NSEG), 256, 0, stream>>>(mbbf, keybf, rawtbf,
      ws + YP_F, ws + MP_F, ws + LP_F);
  k_combine<<<2304, 256, 0, stream>>>(x, ws, out);
}

// Round 3
// 273.980 us; speedup vs baseline: 5.4022x; 1.6578x over previous
//
#include <hip/hip_runtime.h>
#include <math.h>

typedef unsigned short ushort_t;
typedef __attribute__((ext_vector_type(8))) short short8;
typedef __attribute__((ext_vector_type(4))) float float4v;

// Problem constants
#define NB 4
#define C 64
#define CR 32
#define HW 2304
#define LTOT 7470
#define LPAD 7472   // padded V row stride (16B-aligned rows)
#define NSEG 6
#define SEG 1248

// ---- workspace float offsets ----
// Region A: padded conv inputs (convs phase) ALIASED with attention partials.
#define PX0 0          // [4][64][50*50]  640000
#define PX1 640000     // [4][64][45*45]  518400
#define PX2 1158400    // [4][64][40*40]  409600
#define PX3 1568000    // [4][64][35*35]  313600
#define PX4 1881600    // [4][64][30*30]  230400  (end 2112000)
#define YP_F 0         // NSEG*4*2304*64 = 3538944 (attention phase)
#define MP_F 3538944   // NSEG*4*2304 = 55296
#define LP_F 3594240   // 55296 (end 3649536)
// Region B: persistent across phases
#define MBBF_F   3649536 // bf16 queries [n][q][cr]      294912 shorts
#define KEYBF_F  3796992 // bf16 keys    [n][l][cr]      956160 shorts
#define RAWTBF_F 4275072 // bf16 V^T     [n][c][LPAD]    1912832 shorts
// total = 5231488 floats = 20.9 MB

static __device__ __forceinline__ ushort_t f2bf(float f) {
  union { float f; unsigned u; } v; v.f = f;
  unsigned r = v.u + 0x7FFF + ((v.u >> 16) & 1);
  return (ushort_t)(r >> 16);
}

__device__ __forceinline__ float cubicw(float d) {
  float ad = fabsf(d);
  float w1 = (1.25f * ad - 2.25f) * ad * ad + 1.0f;
  float w2 = ((-0.75f * ad + 3.75f) * ad - 6.0f) * ad + 3.0f;
  return ad <= 1.0f ? w1 : (ad < 2.0f ? w2 : 0.0f);
}

// ---------------- pad: zero rings all levels, copy x into padded L0 ----------------
__global__ void k_pad(const float* __restrict__ x, float* __restrict__ ws) {
  int tid = blockIdx.x * 256 + threadIdx.x;
  int Dp, rem, lvl;
  if (tid < 640000)       { Dp = 50; rem = tid;           lvl = 0; }
  else if (tid < 1158400) { Dp = 45; rem = tid - 640000;  lvl = 1; }
  else if (tid < 1568000) { Dp = 40; rem = tid - 1158400; lvl = 2; }
  else if (tid < 1881600) { Dp = 35; rem = tid - 1568000; lvl = 3; }
  else if (tid < 2112000) { Dp = 30; rem = tid - 1881600; lvl = 4; }
  else return;
  int PDD = Dp * Dp;
  int pp = rem % PDD, nc = rem / PDD;
  int py = pp / Dp, px = pp % Dp;
  bool ring = (py == 0) | (py == Dp - 1) | (px == 0) | (px == Dp - 1);
  if (ring) { ws[tid] = 0.f; return; }
  if (lvl == 0) ws[tid] = x[nc * HW + (py - 1) * 48 + (px - 1)];
  // levels 1-4 interior filled by k_resize
}

// ---------------- bicubic resize into padded interiors ----------------
__global__ void k_resize(const float* __restrict__ x, float* __restrict__ ws) {
  int tid = blockIdx.x * 256 + threadIdx.x;
  int D, Dp, rem, base;
  if (tid < 473344)       { D = 43; Dp = 45; rem = tid;           base = PX1; }
  else if (tid < 843008)  { D = 38; Dp = 40; rem = tid - 473344;  base = PX2; }
  else if (tid < 1121792) { D = 33; Dp = 35; rem = tid - 843008;  base = PX3; }
  else                    { D = 28; Dp = 30; rem = tid - 1121792; base = PX4; }
  int DD = D * D;
  int pix = rem % DD, nc = rem / DD;
  int py = pix / D, px = pix % D;
  float scale = 48.0f / (float)D;
  float sy = ((float)py + 0.5f) * scale - 0.5f;
  float sx = ((float)px + 0.5f) * scale - 0.5f;
  float y0f = floorf(sy), x0f = floorf(sx);
  int y0 = (int)y0f, x0 = (int)x0f;
  float ty = sy - y0f, tx = sx - x0f;
  float wy[4], wxv[4];
#pragma unroll
  for (int k = 0; k < 4; k++) {
    wy[k]  = cubicw(ty - (float)(k - 1));
    wxv[k] = cubicw(tx - (float)(k - 1));
  }
  const float* src = x + nc * HW;
  float acc = 0.f;
#pragma unroll
  for (int dy = 0; dy < 4; ++dy) {
    int iy = min(max(y0 - 1 + dy, 0), 47);
    const float* row = src + iy * 48;
    float a = 0.f;
#pragma unroll
    for (int dx = 0; dx < 4; ++dx) {
      int ix = min(max(x0 - 1 + dx, 0), 47);
      a = fmaf(wxv[dx], row[ix], a);
    }
    acc = fmaf(wy[dy], a, acc);
  }
  ws[base + nc * (Dp * Dp) + (py + 1) * Dp + (px + 1)] = acc;
}

// ---------------- query conv 3x3 64->32 pad1: 8 crs/thread, padded input ----------------
__global__ __launch_bounds__(256) void k_qconv(const float* __restrict__ ws,
    const float* __restrict__ wb, const float* __restrict__ bb,
    ushort_t* __restrict__ mbbf) {
  int p = blockIdx.x * 256 + threadIdx.x;
  int n = blockIdx.y >> 2, crg = blockIdx.y & 3;
  int py = p / 48, px = p % 48;
  const float* vbase = ws + PX0 + n * C * 2500 + (py + 1) * 50 + (px + 1);
  const float* wcb = wb + crg * 8 * 576;
  float acc[8];
#pragma unroll
  for (int j = 0; j < 8; j++) acc[j] = bb[crg * 8 + j];
  for (int ic = 0; ic < C; ++ic) {
    const float* s0 = vbase + ic * 2500;
    float v[9];
    v[0] = s0[-51]; v[1] = s0[-50]; v[2] = s0[-49];
    v[3] = s0[-1];  v[4] = s0[0];   v[5] = s0[1];
    v[6] = s0[49];  v[7] = s0[50];  v[8] = s0[51];
#pragma unroll
    for (int j = 0; j < 8; j++) {
      const float* wk = wcb + j * 576 + ic * 9;
#pragma unroll
      for (int tap = 0; tap < 9; tap++) acc[j] = fmaf(wk[tap], v[tap], acc[j]);
    }
  }
  short8 o;
#pragma unroll
  for (int j = 0; j < 8; j++) o[j] = (short)f2bf(acc[j]);
  *(short8*)(mbbf + (size_t)(n * HW + p) * CR + crg * 8) = o;
}

// ---------------- key conv 3x3 64->32 pad1, all levels: 8 crs/thread ----------------
__global__ __launch_bounds__(256) void k_kconv(const float* __restrict__ ws,
    const float* __restrict__ wm, const float* __restrict__ bm,
    ushort_t* __restrict__ keybf) {
  int l = blockIdx.x * 256 + threadIdx.x;
  if (l >= LTOT) return;
  int n = blockIdx.y >> 2, crg = blockIdx.y & 3;
  int D, Dp, p, base;
  if (l < 2304)      { D = 48; Dp = 50; p = l;        base = PX0 + n * C * 2500; }
  else if (l < 4153) { D = 43; Dp = 45; p = l - 2304; base = PX1 + n * C * 2025; }
  else if (l < 5597) { D = 38; Dp = 40; p = l - 4153; base = PX2 + n * C * 1600; }
  else if (l < 6686) { D = 33; Dp = 35; p = l - 5597; base = PX3 + n * C * 1225; }
  else               { D = 28; Dp = 30; p = l - 6686; base = PX4 + n * C * 900; }
  int PDD = Dp * Dp;
  const float* vbase = ws + base + (p / D + 1) * Dp + (p % D + 1);
  const float* wcb = wm + crg * 8 * 576;
  float acc[8];
#pragma unroll
  for (int j = 0; j < 8; j++) acc[j] = bm[crg * 8 + j];
  for (int ic = 0; ic < C; ++ic) {
    const float* s0 = vbase + ic * PDD;
    float v[9];
    v[0] = s0[-Dp - 1]; v[1] = s0[-Dp]; v[2] = s0[-Dp + 1];
    v[3] = s0[-1];      v[4] = s0[0];   v[5] = s0[1];
    v[6] = s0[Dp - 1];  v[7] = s0[Dp];  v[8] = s0[Dp + 1];
#pragma unroll
    for (int j = 0; j < 8; j++) {
      const float* wk = wcb + j * 576 + ic * 9;
#pragma unroll
      for (int tap = 0; tap < 9; tap++) acc[j] = fmaf(wk[tap], v[tap], acc[j]);
    }
  }
  short8 o;
#pragma unroll
  for (int j = 0; j < 8; j++) o[j] = (short)f2bf(acc[j]);
  *(short8*)(keybf + (size_t)(n * LTOT + l) * CR + crg * 8) = o;
}

// ---------------- value conv 1x1 64->64: 8 cs/thread, transposed bf16 out ----------------
__global__ __launch_bounds__(256) void k_vconv(const float* __restrict__ ws,
    const float* __restrict__ wa, const float* __restrict__ ba,
    ushort_t* __restrict__ rawtbf) {
  int l = blockIdx.x * 256 + threadIdx.x;
  if (l >= LTOT) return;
  int n = blockIdx.y >> 3, cg = blockIdx.y & 7;
  int D, Dp, p, base;
  if (l < 2304)      { D = 48; Dp = 50; p = l;        base = PX0 + n * C * 2500; }
  else if (l < 4153) { D = 43; Dp = 45; p = l - 2304; base = PX1 + n * C * 2025; }
  else if (l < 5597) { D = 38; Dp = 40; p = l - 4153; base = PX2 + n * C * 1600; }
  else if (l < 6686) { D = 33; Dp = 35; p = l - 5597; base = PX3 + n * C * 1225; }
  else               { D = 28; Dp = 30; p = l - 6686; base = PX4 + n * C * 900; }
  int PDD = Dp * Dp;
  const float* vbase = ws + base + (p / D + 1) * Dp + (p % D + 1);
  float acc[8];
#pragma unroll
  for (int j = 0; j < 8; j++) acc[j] = ba[cg * 8 + j];
  for (int ic = 0; ic < C; ++ic) {
    float v = vbase[ic * PDD];
#pragma unroll
    for (int j = 0; j < 8; j++) acc[j] = fmaf(wa[(cg * 8 + j) * C + ic], v, acc[j]);
  }
#pragma unroll
  for (int j = 0; j < 8; j++)
    rawtbf[(size_t)(n * C + cg * 8 + j) * LPAD + l] = f2bf(acc[j]);
}

// ---------------- MFMA flash attention over one L segment ----------------
__global__ __launch_bounds__(256) void k_attn(const ushort_t* __restrict__ mb,
    const ushort_t* __restrict__ keyb, const ushort_t* __restrict__ rawt,
    float* __restrict__ Yp, float* __restrict__ mp, float* __restrict__ lp) {
  __shared__ __align__(16) ushort_t KsF[2048];
  __shared__ __align__(16) ushort_t VsF[4096];
  __shared__ __align__(16) ushort_t Pl[4 * 1152];

  int t = threadIdx.x;
  int n = blockIdx.y, seg = blockIdx.z;
  int lane = t & 63, wv = t >> 6;
  int col = lane & 15, quad = lane >> 4;
  int qb = blockIdx.x * 64 + wv * 16;
  int l_begin = seg * SEG;
  int l_end = min(l_begin + SEG, LTOT);

  short8 qA = *(const short8*)(mb + ((size_t)(n * HW + qb + col)) * CR + quad * 8);

  float4v Y[4];
#pragma unroll
  for (int ct = 0; ct < 4; ct++)
#pragma unroll
    for (int r = 0; r < 4; r++) Y[ct][r] = 0.f;
  float m[4], ls[4];
#pragma unroll
  for (int r = 0; r < 4; r++) { m[r] = -INFINITY; ls[r] = 0.f; }

  ushort_t* Pw = Pl + wv * 1152;
  const ushort_t* keyn = keyb + (size_t)n * LTOT * CR;
  const ushort_t* rawn = rawt + (size_t)n * C * LPAD;
  const float4v zero4 = {0.f, 0.f, 0.f, 0.f};

  int kl_off = ((t >> 6) << 4) + (t & 15);
  int kg = (t >> 4) & 3;

  for (int l0 = l_begin; l0 < l_end; l0 += 64) {
    *(uint4*)&KsF[t * 8] =
        *(const uint4*)(keyn + ((size_t)(l0 + kl_off)) * CR + kg * 8);
#pragma unroll
    for (int i = 0; i < 2; i++) {
      int v = t + (i << 8);
      int kt = v >> 8, ct = (v >> 6) & 3, g = (v >> 4) & 3, cc = v & 15;
      *(uint4*)&VsF[v * 8] =
          *(const uint4*)(rawn + ((size_t)(ct * 16 + cc)) * LPAD + l0 + kt * 32 + g * 8);
    }
    __syncthreads();

    float sv[4][4];
#pragma unroll
    for (int tt = 0; tt < 4; tt++) {
      short8 bK = *(const short8*)&KsF[(tt * 64 + lane) * 8];
      float4v S = __builtin_amdgcn_mfma_f32_16x16x32_bf16(qA, bK, zero4, 0, 0, 0);
      int lg = l0 + tt * 16 + col;
      bool ok = lg < l_end;
#pragma unroll
      for (int r = 0; r < 4; r++) sv[tt][r] = ok ? S[r] : -INFINITY;
    }

    float rmax[4];
#pragma unroll
    for (int r = 0; r < 4; r++)
      rmax[r] = fmaxf(fmaxf(sv[0][r], sv[1][r]), fmaxf(sv[2][r], sv[3][r]));
#pragma unroll
    for (int off = 1; off < 16; off <<= 1)
#pragma unroll
      for (int r = 0; r < 4; r++) rmax[r] = fmaxf(rmax[r], __shfl_xor(rmax[r], off));

    float al[4];
#pragma unroll
    for (int r = 0; r < 4; r++) {
      float mn = fmaxf(m[r], rmax[r]);
      al[r] = __expf(m[r] - mn);
      m[r] = mn;
    }
    float rsum[4] = {0.f, 0.f, 0.f, 0.f};
#pragma unroll
    for (int tt = 0; tt < 4; tt++)
#pragma unroll
      for (int r = 0; r < 4; r++) {
        float p = __expf(sv[tt][r] - m[r]);
        rsum[r] += p;
        Pw[(quad * 4 + r) * 72 + tt * 16 + col] = f2bf(p);
      }
#pragma unroll
    for (int off = 1; off < 16; off <<= 1)
#pragma unroll
      for (int r = 0; r < 4; r++) rsum[r] += __shfl_xor(rsum[r], off);
#pragma unroll
    for (int r = 0; r < 4; r++) ls[r] = ls[r] * al[r] + rsum[r];
#pragma unroll
    for (int ct = 0; ct < 4; ct++)
#pragma unroll
      for (int r = 0; r < 4; r++) Y[ct][r] *= al[r];
    __syncthreads();

#pragma unroll
    for (int kt = 0; kt < 2; kt++) {
      short8 aP = *(const short8*)&Pw[col * 72 + kt * 32 + quad * 8];
#pragma unroll
      for (int ct = 0; ct < 4; ct++) {
        short8 bV = *(const short8*)&VsF[(((kt << 2) | ct) * 64 + lane) * 8];
        Y[ct] = __builtin_amdgcn_mfma_f32_16x16x32_bf16(aP, bV, Y[ct], 0, 0, 0);
      }
    }
    __syncthreads();
  }

  float* yo = Yp + ((size_t)(seg * NB + n) * HW + qb) * C;
#pragma unroll
  for (int ct = 0; ct < 4; ct++)
#pragma unroll
    for (int r = 0; r < 4; r++)
      yo[(quad * 4 + r) * C + ct * 16 + col] = Y[ct][r];
  if (col == 0) {
    int base = (seg * NB + n) * HW + qb + quad * 4;
#pragma unroll
    for (int r = 0; r < 4; r++) { mp[base + r] = m[r]; lp[base + r] = ls[r]; }
  }
}

// ---------------- combine segment partials + residual ----------------
__global__ void k_combine(const float* __restrict__ x, const float* __restrict__ ws,
                          float* __restrict__ out) {
  int tid = blockIdx.x * 256 + threadIdx.x;
  int c = tid & 63;
  int t2 = tid >> 6;
  int q = t2 % HW;
  int n = t2 / HW;
  const float* Yv = ws + YP_F;
  const float* mp = ws + MP_F;
  const float* lp = ws + LP_F;
  int i0 = n * HW + q;
  float mm = -INFINITY;
#pragma unroll
  for (int s = 0; s < NSEG; s++) mm = fmaxf(mm, mp[s * NB * HW + i0]);
  float den = 0.f, num = 0.f;
#pragma unroll
  for (int s = 0; s < NSEG; s++) {
    int idx = s * NB * HW + i0;
    float e = __expf(mp[idx] - mm);
    den += lp[idx] * e;
    num += Yv[(size_t)idx * C + c] * e;
  }
  int oi = (n * C + c) * HW + q;
  out[oi] = num / den + x[oi];
}

extern "C" void kernel_launch(void* const* d_in, const int* in_sizes, int n_in,
                              void* d_out, int out_size, void* d_ws, size_t ws_size,
                              hipStream_t stream) {
  const float* x  = (const float*)d_in[0];
  const float* wb = (const float*)d_in[1];
  const float* bb = (const float*)d_in[2];
  const float* wm = (const float*)d_in[3];
  const float* bm = (const float*)d_in[4];
  const float* wa = (const float*)d_in[5];
  const float* ba = (const float*)d_in[6];
  float* out = (float*)d_out;
  float* ws = (float*)d_ws;
  ushort_t* mbbf   = (ushort_t*)(ws + MBBF_F);
  ushort_t* keybf  = (ushort_t*)(ws + KEYBF_F);
  ushort_t* rawtbf = (ushort_t*)(ws + RAWTBF_F);

  k_pad<<<8250, 256, 0, stream>>>(x, ws);
  k_resize<<<5166, 256, 0, stream>>>(x, ws);
  k_qconv<<<dim3(9, 16), 256, 0, stream>>>(ws, wb, bb, mbbf);
  k_kconv<<<dim3(30, 16), 256, 0, stream>>>(ws, wm, bm, keybf);
  k_vconv<<<dim3(30, 32), 256, 0, stream>>>(ws, wa, ba, rawtbf);
  k_attn<<<dim3(36, 4, NSEG), 256, 0, stream>>>(mbbf, keybf, rawtbf,
      ws + YP_F, ws + MP_F, ws + LP_F);
  k_combine<<<2304, 256, 0, stream>>>(x, ws, out);
}

// Round 4
// 220.254 us; speedup vs baseline: 6.7199x; 1.2439x over previous
//
#include <hip/hip_runtime.h>
#include <math.h>

typedef unsigned short ushort_t;
typedef __attribute__((ext_vector_type(8))) short short8;
typedef __attribute__((ext_vector_type(4))) float float4v;

// Problem constants
#define NB 4
#define C 64
#define CR 32
#define HW 2304
#define LTOT 7470
#define LPAD 7472   // padded V row stride
#define NSEG 8
#define SEG 960     // multiple of 64; seg7 = 750 (11 full chunks + 46 tail)
#define LOG2E 1.44269504088896f

// ---- workspace float offsets ----
// Region A: padded conv inputs (conv phase) ALIASED with attention partials.
#define PX0 0          // [4][64][50*50]  640000
#define PX1 640000     // [4][64][45*45]  518400
#define PX2 1158400    // [4][64][40*40]  409600
#define PX3 1568000    // [4][64][35*35]  313600
#define PX4 1881600    // [4][64][30*30]  230400  (end 2112000)
#define YP_F 0         // NSEG*4*2304*64 = 4718592 (attention phase)
#define LP_F 4718592   // NSEG*4*2304 = 73728 (end 4792320)
// Region B: persistent across phases
#define MBBF_F   4792320 // bf16 queries (log2e-scaled) [n][q][cr]  294912 shorts
#define KEYBF_F  4939776 // bf16 keys [n][l][cr]                    956160 shorts
#define RAWTBF_F 5417856 // bf16 V^T  [n][c][LPAD]                  1912832 shorts
// end 6374272 + 1024 slack (tail-chunk OOB staging reads) = 6375296 floats = 25.5 MB

static __device__ __forceinline__ ushort_t f2bf(float f) {
  union { float f; unsigned u; } v; v.f = f;
  unsigned r = v.u + 0x7FFF + ((v.u >> 16) & 1);
  return (ushort_t)(r >> 16);
}

__device__ __forceinline__ float cubicw(float d) {
  float ad = fabsf(d);
  float w1 = (1.25f * ad - 2.25f) * ad * ad + 1.0f;
  float w2 = ((-0.75f * ad + 3.75f) * ad - 6.0f) * ad + 3.0f;
  return ad <= 1.0f ? w1 : (ad < 2.0f ? w2 : 0.0f);
}

// ---------------- pad: zero rings all levels, copy x into padded L0 ----------------
__global__ void k_pad(const float* __restrict__ x, float* __restrict__ ws) {
  int tid = blockIdx.x * 256 + threadIdx.x;
  int Dp, rem, lvl;
  if (tid < 640000)       { Dp = 50; rem = tid;           lvl = 0; }
  else if (tid < 1158400) { Dp = 45; rem = tid - 640000;  lvl = 1; }
  else if (tid < 1568000) { Dp = 40; rem = tid - 1158400; lvl = 2; }
  else if (tid < 1881600) { Dp = 35; rem = tid - 1568000; lvl = 3; }
  else if (tid < 2112000) { Dp = 30; rem = tid - 1881600; lvl = 4; }
  else return;
  int PDD = Dp * Dp;
  int pp = rem % PDD, nc = rem / PDD;
  int py = pp / Dp, px = pp % Dp;
  bool ring = (py == 0) | (py == Dp - 1) | (px == 0) | (px == Dp - 1);
  if (ring) { ws[tid] = 0.f; return; }
  if (lvl == 0) ws[tid] = x[nc * HW + (py - 1) * 48 + (px - 1)];
}

// ---------------- bicubic resize into padded interiors ----------------
__global__ void k_resize(const float* __restrict__ x, float* __restrict__ ws) {
  int tid = blockIdx.x * 256 + threadIdx.x;
  int D, Dp, rem, base;
  if (tid < 473344)       { D = 43; Dp = 45; rem = tid;           base = PX1; }
  else if (tid < 843008)  { D = 38; Dp = 40; rem = tid - 473344;  base = PX2; }
  else if (tid < 1121792) { D = 33; Dp = 35; rem = tid - 843008;  base = PX3; }
  else                    { D = 28; Dp = 30; rem = tid - 1121792; base = PX4; }
  int DD = D * D;
  int pix = rem % DD, nc = rem / DD;
  int py = pix / D, px = pix % D;
  float scale = 48.0f / (float)D;
  float sy = ((float)py + 0.5f) * scale - 0.5f;
  float sx = ((float)px + 0.5f) * scale - 0.5f;
  float y0f = floorf(sy), x0f = floorf(sx);
  int y0 = (int)y0f, x0 = (int)x0f;
  float ty = sy - y0f, tx = sx - x0f;
  float wy[4], wxv[4];
#pragma unroll
  for (int k = 0; k < 4; k++) {
    wy[k]  = cubicw(ty - (float)(k - 1));
    wxv[k] = cubicw(tx - (float)(k - 1));
  }
  const float* src = x + nc * HW;
  float acc = 0.f;
#pragma unroll
  for (int dy = 0; dy < 4; ++dy) {
    int iy = min(max(y0 - 1 + dy, 0), 47);
    const float* row = src + iy * 48;
    float a = 0.f;
#pragma unroll
    for (int dx = 0; dx < 4; ++dx) {
      int ix = min(max(x0 - 1 + dx, 0), 47);
      a = fmaf(wxv[dx], row[ix], a);
    }
    acc = fmaf(wy[dy], a, acc);
  }
  ws[base + nc * (Dp * Dp) + (py + 1) * Dp + (px + 1)] = acc;
}

// ---------------- key conv (all levels) + folded query conv (level 0) ----------------
// grid (30, 16): y = n*4+crg. Blocks x<9 (l<2304) also compute queries (same taps).
__global__ __launch_bounds__(256) void k_kconv(const float* __restrict__ ws,
    const float* __restrict__ wm, const float* __restrict__ bm,
    const float* __restrict__ wb, const float* __restrict__ bb,
    ushort_t* __restrict__ keybf, ushort_t* __restrict__ mbbf) {
  int l = blockIdx.x * 256 + threadIdx.x;
  if (l >= LTOT) return;
  int n = blockIdx.y >> 2, crg = blockIdx.y & 3;
  int D, Dp, p, base;
  if (l < 2304)      { D = 48; Dp = 50; p = l;        base = PX0 + n * C * 2500; }
  else if (l < 4153) { D = 43; Dp = 45; p = l - 2304; base = PX1 + n * C * 2025; }
  else if (l < 5597) { D = 38; Dp = 40; p = l - 4153; base = PX2 + n * C * 1600; }
  else if (l < 6686) { D = 33; Dp = 35; p = l - 5597; base = PX3 + n * C * 1225; }
  else               { D = 28; Dp = 30; p = l - 6686; base = PX4 + n * C * 900; }
  int PDD = Dp * Dp;
  const float* vbase = ws + base + (p / D + 1) * Dp + (p % D + 1);
  const float* wcb = wm + crg * 8 * 576;
  const float* wqb = wb + crg * 8 * 576;
  bool doq = (l < 2304);
  float acc[8], accq[8];
#pragma unroll
  for (int j = 0; j < 8; j++) { acc[j] = bm[crg * 8 + j]; accq[j] = bb[crg * 8 + j]; }
  for (int ic = 0; ic < C; ++ic) {
    const float* s0 = vbase + ic * PDD;
    float v[9];
    v[0] = s0[-Dp - 1]; v[1] = s0[-Dp]; v[2] = s0[-Dp + 1];
    v[3] = s0[-1];      v[4] = s0[0];   v[5] = s0[1];
    v[6] = s0[Dp - 1];  v[7] = s0[Dp];  v[8] = s0[Dp + 1];
#pragma unroll
    for (int j = 0; j < 8; j++) {
      const float* wk = wcb + j * 576 + ic * 9;
#pragma unroll
      for (int tap = 0; tap < 9; tap++) acc[j] = fmaf(wk[tap], v[tap], acc[j]);
    }
    if (doq) {
#pragma unroll
      for (int j = 0; j < 8; j++) {
        const float* wk = wqb + j * 576 + ic * 9;
#pragma unroll
        for (int tap = 0; tap < 9; tap++) accq[j] = fmaf(wk[tap], v[tap], accq[j]);
      }
    }
  }
  short8 o;
#pragma unroll
  for (int j = 0; j < 8; j++) o[j] = (short)f2bf(acc[j]);
  *(short8*)(keybf + (size_t)(n * LTOT + l) * CR + crg * 8) = o;
  if (doq) {
    short8 oq;
#pragma unroll
    for (int j = 0; j < 8; j++) oq[j] = (short)f2bf(accq[j] * LOG2E);  // log2 domain
    *(short8*)(mbbf + (size_t)(n * HW + l) * CR + crg * 8) = oq;
  }
}

// ---------------- value conv 1x1 64->64: 16 cs/thread, transposed bf16 out ----------------
__global__ __launch_bounds__(256) void k_vconv(const float* __restrict__ ws,
    const float* __restrict__ wa, const float* __restrict__ ba,
    ushort_t* __restrict__ rawtbf) {
  int l = blockIdx.x * 256 + threadIdx.x;
  if (l >= LTOT) return;
  int n = blockIdx.y >> 2, cg = blockIdx.y & 3;
  int D, Dp, p, base;
  if (l < 2304)      { D = 48; Dp = 50; p = l;        base = PX0 + n * C * 2500; }
  else if (l < 4153) { D = 43; Dp = 45; p = l - 2304; base = PX1 + n * C * 2025; }
  else if (l < 5597) { D = 38; Dp = 40; p = l - 4153; base = PX2 + n * C * 1600; }
  else if (l < 6686) { D = 33; Dp = 35; p = l - 5597; base = PX3 + n * C * 1225; }
  else               { D = 28; Dp = 30; p = l - 6686; base = PX4 + n * C * 900; }
  int PDD = Dp * Dp;
  const float* vbase = ws + base + (p / D + 1) * Dp + (p % D + 1);
  float acc[16];
#pragma unroll
  for (int j = 0; j < 16; j++) acc[j] = ba[cg * 16 + j];
  for (int ic = 0; ic < C; ++ic) {
    float v = vbase[ic * PDD];
#pragma unroll
    for (int j = 0; j < 16; j++) acc[j] = fmaf(wa[(cg * 16 + j) * C + ic], v, acc[j]);
  }
#pragma unroll
  for (int j = 0; j < 16; j++)
    rawtbf[(size_t)(n * C + cg * 16 + j) * LPAD + l] = f2bf(acc[j]);
}

// ---------------- MFMA flash attention, no-max softmax, one L segment ----------------
__global__ __launch_bounds__(256) void k_attn(const ushort_t* __restrict__ mb,
    const ushort_t* __restrict__ keyb, const ushort_t* __restrict__ rawt,
    float* __restrict__ Yp, float* __restrict__ lp) {
  __shared__ __align__(16) ushort_t KsF[2048];
  __shared__ __align__(16) ushort_t VsF[4096];
  __shared__ __align__(16) ushort_t Pl[4 * 1152];

  int t = threadIdx.x;
  int n = blockIdx.y, seg = blockIdx.z;
  int lane = t & 63, wv = t >> 6;
  int col = lane & 15, quad = lane >> 4;
  int qb = blockIdx.x * 64 + wv * 16;
  int l_begin = seg * SEG;
  int l_end = min(l_begin + SEG, LTOT);
  int nfull = (l_end - l_begin) >> 6;
  int rem = (l_end - l_begin) & 63;

  // Q A-frag (already in log2 domain): A[m=col][k=quad*8+j]
  short8 qA = *(const short8*)(mb + ((size_t)(n * HW + qb + col)) * CR + quad * 8);

  float4v Y[4];
#pragma unroll
  for (int ct = 0; ct < 4; ct++)
#pragma unroll
    for (int r = 0; r < 4; r++) Y[ct][r] = 0.f;
  float ls[4] = {0.f, 0.f, 0.f, 0.f};

  ushort_t* Pw = Pl + wv * 1152;
  const ushort_t* keyn = keyb + (size_t)n * LTOT * CR;
  const ushort_t* rawn = rawt + (size_t)n * C * LPAD;
  const float4v zero4 = {0.f, 0.f, 0.f, 0.f};

  int kl_off = ((t >> 6) << 4) + (t & 15);
  int kg = (t >> 4) & 3;

  for (int ch = 0; ch <= nfull; ++ch) {   // last iteration = masked tail (if rem)
    bool tail = (ch == nfull);
    if (tail && rem == 0) break;
    int l0 = l_begin + ch * 64;

    // ---- stage K/V (tail reads run into adjacent allocated ws; masked below) ----
    *(uint4*)&KsF[t * 8] =
        *(const uint4*)(keyn + ((size_t)(l0 + kl_off)) * CR + kg * 8);
#pragma unroll
    for (int i = 0; i < 2; i++) {
      int v = t + (i << 8);
      int kt = v >> 8, ct = (v >> 6) & 3, g = (v >> 4) & 3, cc = v & 15;
      *(uint4*)&VsF[v * 8] =
          *(const uint4*)(rawn + ((size_t)(ct * 16 + cc)) * LPAD + l0 + kt * 32 + g * 8);
    }
    __syncthreads();

    // ---- scores + p = exp2(s), accumulate denominator partials ----
#pragma unroll
    for (int tt = 0; tt < 4; tt++) {
      short8 bK = *(const short8*)&KsF[(tt * 64 + lane) * 8];
      float4v S = __builtin_amdgcn_mfma_f32_16x16x32_bf16(qA, bK, zero4, 0, 0, 0);
      bool ok = !tail || (tt * 16 + col < rem);
#pragma unroll
      for (int r = 0; r < 4; r++) {
        float p = __builtin_amdgcn_exp2f(S[r]);
        p = ok ? p : 0.f;
        ls[r] += p;
        union { float f; unsigned u; } cv; cv.f = p;
        Pw[(quad * 4 + r) * 72 + tt * 16 + col] = (ushort_t)((cv.u + 0x8000u) >> 16);
      }
    }
    __syncthreads();

    // ---- PV ----
#pragma unroll
    for (int kt = 0; kt < 2; kt++) {
      short8 aP = *(const short8*)&Pw[col * 72 + kt * 32 + quad * 8];
#pragma unroll
      for (int ct = 0; ct < 4; ct++) {
        short8 bV = *(const short8*)&VsF[(((kt << 2) | ct) * 64 + lane) * 8];
        Y[ct] = __builtin_amdgcn_mfma_f32_16x16x32_bf16(aP, bV, Y[ct], 0, 0, 0);
      }
    }
    __syncthreads();
  }

  // reduce denominator across the 16 lanes of each quad (rows = quad*4+r)
#pragma unroll
  for (int off = 1; off < 16; off <<= 1)
#pragma unroll
    for (int r = 0; r < 4; r++) ls[r] += __shfl_xor(ls[r], off);

  float* yo = Yp + ((size_t)(seg * NB + n) * HW + qb) * C;
#pragma unroll
  for (int ct = 0; ct < 4; ct++)
#pragma unroll
    for (int r = 0; r < 4; r++)
      yo[(quad * 4 + r) * C + ct * 16 + col] = Y[ct][r];
  if (col == 0) {
    int base = (seg * NB + n) * HW + qb + quad * 4;
#pragma unroll
    for (int r = 0; r < 4; r++) lp[base + r] = ls[r];
  }
}

// ---------------- combine segment partials + residual (no exp needed) ----------------
__global__ void k_combine(const float* __restrict__ x, const float* __restrict__ ws,
                          float* __restrict__ out) {
  int tid = blockIdx.x * 256 + threadIdx.x;
  int c = tid & 63;
  int t2 = tid >> 6;
  int q = t2 % HW;
  int n = t2 / HW;
  const float* Yv = ws + YP_F;
  const float* lpv = ws + LP_F;
  int i0 = n * HW + q;
  float den = 0.f, num = 0.f;
#pragma unroll
  for (int s = 0; s < NSEG; s++) {
    int idx = s * NB * HW + i0;
    den += lpv[idx];
    num += Yv[(size_t)idx * C + c];
  }
  int oi = (n * C + c) * HW + q;
  out[oi] = num / den + x[oi];
}

extern "C" void kernel_launch(void* const* d_in, const int* in_sizes, int n_in,
                              void* d_out, int out_size, void* d_ws, size_t ws_size,
                              hipStream_t stream) {
  const float* x  = (const float*)d_in[0];
  const float* wb = (const float*)d_in[1];
  const float* bb = (const float*)d_in[2];
  const float* wm = (const float*)d_in[3];
  const float* bm = (const float*)d_in[4];
  const float* wa = (const float*)d_in[5];
  const float* ba = (const float*)d_in[6];
  float* out = (float*)d_out;
  float* ws = (float*)d_ws;
  ushort_t* mbbf   = (ushort_t*)(ws + MBBF_F);
  ushort_t* keybf  = (ushort_t*)(ws + KEYBF_F);
  ushort_t* rawtbf = (ushort_t*)(ws + RAWTBF_F);

  k_pad<<<8250, 256, 0, stream>>>(x, ws);
  k_resize<<<5166, 256, 0, stream>>>(x, ws);
  k_kconv<<<dim3(30, 16), 256, 0, stream>>>(ws, wm, bm, wb, bb, keybf, mbbf);
  k_vconv<<<dim3(30, 16), 256, 0, stream>>>(ws, wa, ba, rawtbf);
  k_attn<<<dim3(36, 4, NSEG), 256, 0, stream>>>(mbbf, keybf, rawtbf,
      ws + YP_F, ws + LP_F);
  k_combine<<<2304, 256, 0, stream>>>(x, ws, out);
}

// Round 5
// 156.656 us; speedup vs baseline: 9.4480x; 1.4060x over previous
//
#include <hip/hip_runtime.h>
#include <math.h>

typedef unsigned short ushort_t;
typedef __attribute__((ext_vector_type(8))) short short8;
typedef __attribute__((ext_vector_type(4))) float float4v;

// Problem constants
#define NB 4
#define C 64
#define CR 32
#define HW 2304
#define LTOT 7470
#define LPAD 7472
#define NSEG 8
#define SEG 960
#define LOG2E 1.44269504088896f

// ---- workspace float offsets ----
// Region A (aliased): conv phase: XT bf16 [33000 px][64 ic] = 2112000 shorts
//                     attn phase: YP + LP
#define YP_F 0         // NSEG*4*2304*64 = 4718592
#define LP_F 4718592   // NSEG*4*2304 = 73728 (end 4792320)
// Persistent region
#define MBBF_F   4792320 // bf16 queries (log2e-scaled) [n][q][32]   294912 shorts
#define KEYBF_F  4939776 // bf16 keys [n][l][32]                     956160 shorts
#define RAWTBF_F 5417856 // bf16 V^T  [n][c][LPAD]                   1912832 shorts
#define WPK_F    6374272 // packed key  weights 36 frags*512 shorts
#define WPQ_F    6383488 // packed query weights 36*512
#define WPV_F    6392704 // packed value weights 8*512 (end 6394752 = 25.6 MB)

static __device__ __forceinline__ ushort_t f2bf(float f) {
  union { float f; unsigned u; } v; v.f = f;
  unsigned r = v.u + 0x7FFF + ((v.u >> 16) & 1);
  return (ushort_t)(r >> 16);
}

__device__ __forceinline__ float cubicw(float d) {
  float ad = fabsf(d);
  float w1 = (1.25f * ad - 2.25f) * ad * ad + 1.0f;
  float w2 = ((-0.75f * ad + 3.75f) * ad - 6.0f) * ad + 3.0f;
  return ad <= 1.0f ? w1 : (ad < 2.0f ? w2 : 0.0f);
}

// ---------------- zero the xt buffer (rings become zero padding) ----------------
__global__ void k_zero(ushort_t* __restrict__ xt) {
  int i = blockIdx.x * 256 + threadIdx.x;
  if (i < 264000) {
    uint4 z = {0u, 0u, 0u, 0u};
    *(uint4*)(xt + (size_t)i * 8) = z;
  }
}

// ---------------- level-0: x [n][c][48x48] -> xt [pp][64c] via LDS transpose ----------------
__global__ __launch_bounds__(256) void k_pad0(const float* __restrict__ x,
                                              ushort_t* __restrict__ xt) {
  __shared__ float tile[64][49];
  int py = blockIdx.x, n = blockIdx.y, t = threadIdx.x;
#pragma unroll
  for (int i = 0; i < 12; i++) {
    int idx = i * 256 + t;            // 3072 = 64c * 48px
    int c = idx / 48, px = idx % 48;
    tile[c][px] = x[(size_t)(n * 64 + c) * HW + py * 48 + px];
  }
  __syncthreads();
#pragma unroll
  for (int i = 0; i < 12; i++) {
    int idx = i * 256 + t;
    int c = idx & 63, px = idx >> 6;
    xt[(size_t)(n * 2500 + (py + 1) * 50 + px + 1) * 64 + c] = f2bf(tile[c][px]);
  }
}

// ---------------- bicubic resize: x -> xt interiors, levels 1-4 ----------------
__global__ void k_resize(const float* __restrict__ x, ushort_t* __restrict__ xt) {
  int tid = blockIdx.x * 256 + threadIdx.x;
  int D, Dp, PDD, rem, pixb;
  if (tid < 473344)       { D = 43; Dp = 45; PDD = 2025; rem = tid;           pixb = 10000; }
  else if (tid < 843008)  { D = 38; Dp = 40; PDD = 1600; rem = tid - 473344;  pixb = 18100; }
  else if (tid < 1121792) { D = 33; Dp = 35; PDD = 1225; rem = tid - 843008;  pixb = 24500; }
  else                    { D = 28; Dp = 30; PDD = 900;  rem = tid - 1121792; pixb = 29400; }
  int DD = D * D;
  int pix = rem % DD, nc = rem / DD;
  int py = pix / D, px = pix % D;
  float scale = 48.0f / (float)D;
  float sy = ((float)py + 0.5f) * scale - 0.5f;
  float sx = ((float)px + 0.5f) * scale - 0.5f;
  float y0f = floorf(sy), x0f = floorf(sx);
  int y0 = (int)y0f, x0 = (int)x0f;
  float ty = sy - y0f, tx = sx - x0f;
  float wy[4], wxv[4];
#pragma unroll
  for (int k = 0; k < 4; k++) {
    wy[k]  = cubicw(ty - (float)(k - 1));
    wxv[k] = cubicw(tx - (float)(k - 1));
  }
  const float* src = x + (size_t)nc * HW;
  float acc = 0.f;
#pragma unroll
  for (int dy = 0; dy < 4; ++dy) {
    int iy = min(max(y0 - 1 + dy, 0), 47);
    const float* row = src + iy * 48;
    float a = 0.f;
#pragma unroll
    for (int dx = 0; dx < 4; ++dx) {
      int ix = min(max(x0 - 1 + dx, 0), 47);
      a = fmaf(wxv[dx], row[ix], a);
    }
    acc = fmaf(wy[dy], a, acc);
  }
  int n = nc >> 6, c = nc & 63;
  xt[(size_t)(pixb + n * PDD + (py + 1) * Dp + (px + 1)) * 64 + c] = f2bf(acc);
}

// ---------------- pack conv weights into MFMA B-frag order ----------------
// wpk/wpq: frag f=(tap*2+half)*2+crt : lane(n=cr=crt*16+col, k=half*32+kg*8+j)
// wpv: frag f=half*4+vt : lane(n=c=vt*16+col, k=half*32+kg*8+j)
__global__ void k_wpack(const float* __restrict__ wm, const float* __restrict__ wb,
                        const float* __restrict__ wa, ushort_t* __restrict__ wpk,
                        ushort_t* __restrict__ wpq, ushort_t* __restrict__ wpv) {
  int tid = blockIdx.x * 256 + threadIdx.x;
  if (tid >= 5120) return;
  int lane = tid & 63, col = lane & 15, kg = lane >> 4;
  if (tid < 4608) {
    int f = (tid >> 6) % 36;
    bool isq = tid >= 2304;
    int tap = f >> 2, half = (f >> 1) & 1, crt = f & 1;
    int cr = crt * 16 + col;
    int ic0 = half * 32 + kg * 8;
    const float* w = isq ? wb : wm;
    short8 v;
#pragma unroll
    for (int j = 0; j < 8; j++) v[j] = (short)f2bf(w[cr * 576 + (ic0 + j) * 9 + tap]);
    *(short8*)((isq ? wpq : wpk) + (size_t)f * 512 + lane * 8) = v;
  } else {
    int id = tid - 4608;
    int f = id >> 6;                    // 0..7
    int half = f >> 2, vt = f & 3;
    int c = vt * 16 + col, ic0 = half * 32 + kg * 8;
    short8 v;
#pragma unroll
    for (int j = 0; j < 8; j++) v[j] = (short)f2bf(wa[c * 64 + ic0 + j]);
    *(short8*)(wpv + (size_t)f * 512 + lane * 8) = v;
  }
}

// ---------------- all convs as implicit-GEMM MFMA ----------------
// Wave-unit = (tile of 16 pixels, crtile of 16). 469 tiles * 2 crt * 4 n.
// D[px=quad*4+r][out=lane&15]; A-frag = im2col from xt (1 b128 global load
// per tap-half); B-frag = packed weights (b128 global, L1/L2 resident).
__global__ __launch_bounds__(256) void k_conv(const ushort_t* __restrict__ xt,
    const ushort_t* __restrict__ wpk, const ushort_t* __restrict__ wpq,
    const ushort_t* __restrict__ wpv, const float* __restrict__ bm,
    const float* __restrict__ bb, const float* __restrict__ ba,
    ushort_t* __restrict__ keybf, ushort_t* __restrict__ mbbf,
    ushort_t* __restrict__ rawtbf) {
  int t = threadIdx.x;
  int unit = blockIdx.x * 4 + (t >> 6);
  if (unit >= 938) return;
  int lane = t & 63, col = lane & 15, quad = lane >> 4;
  int n = blockIdx.y;
  int tile = unit >> 1, crt = unit & 1;
  int D, Dp, PDD, DD, pixb, lb, tloc;
  if (tile < 144)      { D = 48; Dp = 50; PDD = 2500; DD = 2304; pixb = 0;     lb = 0;    tloc = tile; }
  else if (tile < 260) { D = 43; Dp = 45; PDD = 2025; DD = 1849; pixb = 10000; lb = 2304; tloc = tile - 144; }
  else if (tile < 351) { D = 38; Dp = 40; PDD = 1600; DD = 1444; pixb = 18100; lb = 4153; tloc = tile - 260; }
  else if (tile < 420) { D = 33; Dp = 35; PDD = 1225; DD = 1089; pixb = 24500; lb = 5597; tloc = tile - 351; }
  else                 { D = 28; Dp = 30; PDD = 900;  DD = 784;  pixb = 29400; lb = 6686; tloc = tile - 420; }
  bool lvl0 = (tile < 144);

  int p = tloc * 16 + col;
  int pv = min(p, DD - 1);
  int py = pv / D, px = pv - py * D;
  const ushort_t* xb = xt + ((size_t)(pixb + n * PDD + (py + 1) * Dp + (px + 1))) * 64 + quad * 8;

  float4v Dk = {0.f, 0.f, 0.f, 0.f};
  float4v Dq = {0.f, 0.f, 0.f, 0.f};
  float4v Dv0 = {0.f, 0.f, 0.f, 0.f};
  float4v Dv1 = {0.f, 0.f, 0.f, 0.f};

#pragma unroll
  for (int dy = -1; dy <= 1; dy++) {
#pragma unroll
    for (int dx = -1; dx <= 1; dx++) {
      int tap = (dy + 1) * 3 + (dx + 1);
      const ushort_t* ab = xb + (dy * Dp + dx) * 64;
#pragma unroll
      for (int half = 0; half < 2; half++) {
        short8 A = *(const short8*)(ab + half * 32);
        int f = (tap * 2 + half) * 2 + crt;
        short8 Bk = *(const short8*)(wpk + (size_t)f * 512 + lane * 8);
        Dk = __builtin_amdgcn_mfma_f32_16x16x32_bf16(A, Bk, Dk, 0, 0, 0);
        if (lvl0) {
          short8 Bq = *(const short8*)(wpq + (size_t)f * 512 + lane * 8);
          Dq = __builtin_amdgcn_mfma_f32_16x16x32_bf16(A, Bq, Dq, 0, 0, 0);
        }
        if (tap == 4) {
          short8 Bv0 = *(const short8*)(wpv + (size_t)(half * 4 + crt * 2) * 512 + lane * 8);
          short8 Bv1 = *(const short8*)(wpv + (size_t)(half * 4 + crt * 2 + 1) * 512 + lane * 8);
          Dv0 = __builtin_amdgcn_mfma_f32_16x16x32_bf16(A, Bv0, Dv0, 0, 0, 0);
          Dv1 = __builtin_amdgcn_mfma_f32_16x16x32_bf16(A, Bv1, Dv1, 0, 0, 0);
        }
      }
    }
  }

  float biask = bm[crt * 16 + col];
  float biasq = bb[crt * 16 + col];
  float biasv0 = ba[crt * 32 + col];
  float biasv1 = ba[crt * 32 + 16 + col];
  int prow = tloc * 16 + quad * 4;
#pragma unroll
  for (int r = 0; r < 4; r++) {
    if (prow + r < DD) {
      int l = lb + prow + r;
      keybf[(size_t)(n * LTOT + l) * 32 + crt * 16 + col] = f2bf(Dk[r] + biask);
      if (lvl0) mbbf[(size_t)(n * HW + l) * 32 + crt * 16 + col] = f2bf((Dq[r] + biasq) * LOG2E);
      rawtbf[(size_t)(n * 64 + crt * 32 + col) * LPAD + l] = f2bf(Dv0[r] + biasv0);
      rawtbf[(size_t)(n * 64 + crt * 32 + 16 + col) * LPAD + l] = f2bf(Dv1[r] + biasv1);
    }
  }
}

// ---------------- MFMA flash attention, no-max softmax, one L segment ----------------
__global__ __launch_bounds__(256) void k_attn(const ushort_t* __restrict__ mb,
    const ushort_t* __restrict__ keyb, const ushort_t* __restrict__ rawt,
    float* __restrict__ Yp, float* __restrict__ lp) {
  __shared__ __align__(16) ushort_t KsF[2048];
  __shared__ __align__(16) ushort_t VsF[4096];
  __shared__ __align__(16) ushort_t Pl[4 * 1152];

  int t = threadIdx.x;
  int n = blockIdx.y, seg = blockIdx.z;
  int lane = t & 63, wv = t >> 6;
  int col = lane & 15, quad = lane >> 4;
  int qb = blockIdx.x * 64 + wv * 16;
  int l_begin = seg * SEG;
  int l_end = min(l_begin + SEG, LTOT);
  int nfull = (l_end - l_begin) >> 6;
  int rem = (l_end - l_begin) & 63;

  short8 qA = *(const short8*)(mb + ((size_t)(n * HW + qb + col)) * CR + quad * 8);

  float4v Y[4];
#pragma unroll
  for (int ct = 0; ct < 4; ct++)
#pragma unroll
    for (int r = 0; r < 4; r++) Y[ct][r] = 0.f;
  float ls[4] = {0.f, 0.f, 0.f, 0.f};

  ushort_t* Pw = Pl + wv * 1152;
  const ushort_t* keyn = keyb + (size_t)n * LTOT * CR;
  const ushort_t* rawn = rawt + (size_t)n * C * LPAD;
  const float4v zero4 = {0.f, 0.f, 0.f, 0.f};

  int kl_off = ((t >> 6) << 4) + (t & 15);
  int kg = (t >> 4) & 3;

  for (int ch = 0; ch <= nfull; ++ch) {
    bool tail = (ch == nfull);
    if (tail && rem == 0) break;
    int l0 = l_begin + ch * 64;

    *(uint4*)&KsF[t * 8] =
        *(const uint4*)(keyn + ((size_t)(l0 + kl_off)) * CR + kg * 8);
#pragma unroll
    for (int i = 0; i < 2; i++) {
      int v = t + (i << 8);
      int kt = v >> 8, ct = (v >> 6) & 3, g = (v >> 4) & 3, cc = v & 15;
      *(uint4*)&VsF[v * 8] =
          *(const uint4*)(rawn + ((size_t)(ct * 16 + cc)) * LPAD + l0 + kt * 32 + g * 8);
    }
    __syncthreads();

#pragma unroll
    for (int tt = 0; tt < 4; tt++) {
      short8 bK = *(const short8*)&KsF[(tt * 64 + lane) * 8];
      float4v S = __builtin_amdgcn_mfma_f32_16x16x32_bf16(qA, bK, zero4, 0, 0, 0);
      bool ok = !tail || (tt * 16 + col < rem);
#pragma unroll
      for (int r = 0; r < 4; r++) {
        float p = __builtin_amdgcn_exp2f(S[r]);
        p = ok ? p : 0.f;
        ls[r] += p;
        union { float f; unsigned u; } cv; cv.f = p;
        Pw[(quad * 4 + r) * 72 + tt * 16 + col] = (ushort_t)((cv.u + 0x8000u) >> 16);
      }
    }
    __syncthreads();

#pragma unroll
    for (int kt = 0; kt < 2; kt++) {
      short8 aP = *(const short8*)&Pw[col * 72 + kt * 32 + quad * 8];
#pragma unroll
      for (int ct = 0; ct < 4; ct++) {
        short8 bV = *(const short8*)&VsF[(((kt << 2) | ct) * 64 + lane) * 8];
        Y[ct] = __builtin_amdgcn_mfma_f32_16x16x32_bf16(aP, bV, Y[ct], 0, 0, 0);
      }
    }
    __syncthreads();
  }

#pragma unroll
  for (int off = 1; off < 16; off <<= 1)
#pragma unroll
    for (int r = 0; r < 4; r++) ls[r] += __shfl_xor(ls[r], off);

  float* yo = Yp + ((size_t)(seg * NB + n) * HW + qb) * C;
#pragma unroll
  for (int ct = 0; ct < 4; ct++)
#pragma unroll
    for (int r = 0; r < 4; r++)
      yo[(quad * 4 + r) * C + ct * 16 + col] = Y[ct][r];
  if (col == 0) {
    int base = (seg * NB + n) * HW + qb + quad * 4;
#pragma unroll
    for (int r = 0; r < 4; r++) lp[base + r] = ls[r];
  }
}

// ---------------- combine segment partials + residual ----------------
__global__ void k_combine(const float* __restrict__ x, const float* __restrict__ ws,
                          float* __restrict__ out) {
  int tid = blockIdx.x * 256 + threadIdx.x;
  int c = tid & 63;
  int t2 = tid >> 6;
  int q = t2 % HW;
  int n = t2 / HW;
  const float* Yv = ws + YP_F;
  const float* lpv = ws + LP_F;
  int i0 = n * HW + q;
  float den = 0.f, num = 0.f;
#pragma unroll
  for (int s = 0; s < NSEG; s++) {
    int idx = s * NB * HW + i0;
    den += lpv[idx];
    num += Yv[(size_t)idx * C + c];
  }
  int oi = (n * C + c) * HW + q;
  out[oi] = num / den + x[oi];
}

extern "C" void kernel_launch(void* const* d_in, const int* in_sizes, int n_in,
                              void* d_out, int out_size, void* d_ws, size_t ws_size,
                              hipStream_t stream) {
  const float* x  = (const float*)d_in[0];
  const float* wb = (const float*)d_in[1];
  const float* bb = (const float*)d_in[2];
  const float* wm = (const float*)d_in[3];
  const float* bm = (const float*)d_in[4];
  const float* wa = (const float*)d_in[5];
  const float* ba = (const float*)d_in[6];
  float* out = (float*)d_out;
  float* ws = (float*)d_ws;
  ushort_t* xt     = (ushort_t*)ws;                 // region A, conv phase
  ushort_t* mbbf   = (ushort_t*)(ws + MBBF_F);
  ushort_t* keybf  = (ushort_t*)(ws + KEYBF_F);
  ushort_t* rawtbf = (ushort_t*)(ws + RAWTBF_F);
  ushort_t* wpk    = (ushort_t*)(ws + WPK_F);
  ushort_t* wpq    = (ushort_t*)(ws + WPQ_F);
  ushort_t* wpv    = (ushort_t*)(ws + WPV_F);

  k_zero<<<1032, 256, 0, stream>>>(xt);
  k_pad0<<<dim3(48, 4), 256, 0, stream>>>(x, xt);
  k_resize<<<5166, 256, 0, stream>>>(x, xt);
  k_wpack<<<20, 256, 0, stream>>>(wm, wb, wa, wpk, wpq, wpv);
  k_conv<<<dim3(235, 4), 256, 0, stream>>>(xt, wpk, wpq, wpv, bm, bb, ba,
                                           keybf, mbbf, rawtbf);
  k_attn<<<dim3(36, 4, NSEG), 256, 0, stream>>>(mbbf, keybf, rawtbf,
      ws + YP_F, ws + LP_F);
  k_combine<<<2304, 256, 0, stream>>>(x, ws, out);
}

// Round 6
// 154.093 us; speedup vs baseline: 9.6051x; 1.0166x over previous
//
#include <hip/hip_runtime.h>
#include <math.h>

typedef unsigned short ushort_t;
typedef __attribute__((ext_vector_type(8))) short short8;
typedef __attribute__((ext_vector_type(4))) float float4v;

// Problem constants
#define NB 4
#define C 64
#define CR 32
#define HW 2304
#define LTOT 7470
#define LPAD 7472
#define NSEG 15
#define SEG 512
#define LOG2E 1.44269504088896f

// ---- workspace float offsets ----
// Region A (aliased): conv phase: XT bf16 [33000 px][64 ic] = 2112000 shorts
//                     attn phase: YP + LP
#define YP_F 0            // NSEG*4*2304*64 = 8847360
#define LP_F 8847360      // NSEG*4*2304 = 138240 (end 8985600)
// Persistent region
#define MBBF_F   8985600  // bf16 queries (log2e-scaled) [n][q][32]   294912 sh
#define KEYBF_F  9133056  // bf16 keys [n][l][32]                     956160 sh
#define RAWTBF_F 9611136  // bf16 V^T  [n][c][LPAD]                   1912832 sh
#define WPK_F    10567552 // packed key weights 36 frags*512 sh
#define WPQ_F    10576768 // packed query weights 36*512
#define WPV_F    10585984 // packed value weights 8*512 (end 10588032 = 42.4 MB)

static __device__ __forceinline__ ushort_t f2bf(float f) {
  union { float f; unsigned u; } v; v.f = f;
  unsigned r = v.u + 0x7FFF + ((v.u >> 16) & 1);
  return (ushort_t)(r >> 16);
}

__device__ __forceinline__ float cubicw(float d) {
  float ad = fabsf(d);
  float w1 = (1.25f * ad - 2.25f) * ad * ad + 1.0f;
  float w2 = ((-0.75f * ad + 3.75f) * ad - 6.0f) * ad + 3.0f;
  return ad <= 1.0f ? w1 : (ad < 2.0f ? w2 : 0.0f);
}

// ---------------- zero the xt buffer (rings become zero padding) ----------------
__global__ void k_zero(ushort_t* __restrict__ xt) {
  int i = blockIdx.x * 256 + threadIdx.x;
  if (i < 264000) {
    uint4 z = {0u, 0u, 0u, 0u};
    *(uint4*)(xt + (size_t)i * 8) = z;
  }
}

// ---------------- level-0: x [n][c][48x48] -> xt [pp][64c] via LDS transpose ----------------
__global__ __launch_bounds__(256) void k_pad0(const float* __restrict__ x,
                                              ushort_t* __restrict__ xt) {
  __shared__ float tile[64][49];
  int py = blockIdx.x, n = blockIdx.y, t = threadIdx.x;
#pragma unroll
  for (int i = 0; i < 12; i++) {
    int idx = i * 256 + t;
    int c = idx / 48, px = idx % 48;
    tile[c][px] = x[(size_t)(n * 64 + c) * HW + py * 48 + px];
  }
  __syncthreads();
#pragma unroll
  for (int i = 0; i < 12; i++) {
    int idx = i * 256 + t;
    int c = idx & 63, px = idx >> 6;
    xt[(size_t)(n * 2500 + (py + 1) * 50 + px + 1) * 64 + c] = f2bf(tile[c][px]);
  }
}

// ---------------- bicubic resize: x -> xt interiors, levels 1-4 ----------------
__global__ void k_resize(const float* __restrict__ x, ushort_t* __restrict__ xt) {
  int tid = blockIdx.x * 256 + threadIdx.x;
  int D, Dp, PDD, rem, pixb;
  if (tid < 473344)       { D = 43; Dp = 45; PDD = 2025; rem = tid;           pixb = 10000; }
  else if (tid < 843008)  { D = 38; Dp = 40; PDD = 1600; rem = tid - 473344;  pixb = 18100; }
  else if (tid < 1121792) { D = 33; Dp = 35; PDD = 1225; rem = tid - 843008;  pixb = 24500; }
  else                    { D = 28; Dp = 30; PDD = 900;  rem = tid - 1121792; pixb = 29400; }
  int DD = D * D;
  int pix = rem % DD, nc = rem / DD;
  int py = pix / D, px = pix % D;
  float scale = 48.0f / (float)D;
  float sy = ((float)py + 0.5f) * scale - 0.5f;
  float sx = ((float)px + 0.5f) * scale - 0.5f;
  float y0f = floorf(sy), x0f = floorf(sx);
  int y0 = (int)y0f, x0 = (int)x0f;
  float ty = sy - y0f, tx = sx - x0f;
  float wy[4], wxv[4];
#pragma unroll
  for (int k = 0; k < 4; k++) {
    wy[k]  = cubicw(ty - (float)(k - 1));
    wxv[k] = cubicw(tx - (float)(k - 1));
  }
  const float* src = x + (size_t)nc * HW;
  float acc = 0.f;
#pragma unroll
  for (int dy = 0; dy < 4; ++dy) {
    int iy = min(max(y0 - 1 + dy, 0), 47);
    const float* row = src + iy * 48;
    float a = 0.f;
#pragma unroll
    for (int dx = 0; dx < 4; ++dx) {
      int ix = min(max(x0 - 1 + dx, 0), 47);
      a = fmaf(wxv[dx], row[ix], a);
    }
    acc = fmaf(wy[dy], a, acc);
  }
  int n = nc >> 6, c = nc & 63;
  xt[(size_t)(pixb + n * PDD + (py + 1) * Dp + (px + 1)) * 64 + c] = f2bf(acc);
}

// ---------------- pack conv weights into MFMA B-frag order ----------------
__global__ void k_wpack(const float* __restrict__ wm, const float* __restrict__ wb,
                        const float* __restrict__ wa, ushort_t* __restrict__ wpk,
                        ushort_t* __restrict__ wpq, ushort_t* __restrict__ wpv) {
  int tid = blockIdx.x * 256 + threadIdx.x;
  if (tid >= 5120) return;
  int lane = tid & 63, col = lane & 15, kg = lane >> 4;
  if (tid < 4608) {
    int f = (tid >> 6) % 36;
    bool isq = tid >= 2304;
    int tap = f >> 2, half = (f >> 1) & 1, crt = f & 1;
    int cr = crt * 16 + col;
    int ic0 = half * 32 + kg * 8;
    const float* w = isq ? wb : wm;
    short8 v;
#pragma unroll
    for (int j = 0; j < 8; j++) v[j] = (short)f2bf(w[cr * 576 + (ic0 + j) * 9 + tap]);
    *(short8*)((isq ? wpq : wpk) + (size_t)f * 512 + lane * 8) = v;
  } else {
    int id = tid - 4608;
    int f = id >> 6;
    int half = f >> 2, vt = f & 3;
    int c = vt * 16 + col, ic0 = half * 32 + kg * 8;
    short8 v;
#pragma unroll
    for (int j = 0; j < 8; j++) v[j] = (short)f2bf(wa[c * 64 + ic0 + j]);
    *(short8*)(wpv + (size_t)f * 512 + lane * 8) = v;
  }
}

// ---------------- all convs as implicit-GEMM MFMA ----------------
__global__ __launch_bounds__(256) void k_conv(const ushort_t* __restrict__ xt,
    const ushort_t* __restrict__ wpk, const ushort_t* __restrict__ wpq,
    const ushort_t* __restrict__ wpv, const float* __restrict__ bm,
    const float* __restrict__ bb, const float* __restrict__ ba,
    ushort_t* __restrict__ keybf, ushort_t* __restrict__ mbbf,
    ushort_t* __restrict__ rawtbf) {
  int t = threadIdx.x;
  int unit = blockIdx.x * 4 + (t >> 6);
  if (unit >= 938) return;
  int lane = t & 63, col = lane & 15, quad = lane >> 4;
  int n = blockIdx.y;
  int tile = unit >> 1, crt = unit & 1;
  int D, Dp, PDD, DD, pixb, lb, tloc;
  if (tile < 144)      { D = 48; Dp = 50; PDD = 2500; DD = 2304; pixb = 0;     lb = 0;    tloc = tile; }
  else if (tile < 260) { D = 43; Dp = 45; PDD = 2025; DD = 1849; pixb = 10000; lb = 2304; tloc = tile - 144; }
  else if (tile < 351) { D = 38; Dp = 40; PDD = 1600; DD = 1444; pixb = 18100; lb = 4153; tloc = tile - 260; }
  else if (tile < 420) { D = 33; Dp = 35; PDD = 1225; DD = 1089; pixb = 24500; lb = 5597; tloc = tile - 351; }
  else                 { D = 28; Dp = 30; PDD = 900;  DD = 784;  pixb = 29400; lb = 6686; tloc = tile - 420; }
  bool lvl0 = (tile < 144);

  int p = tloc * 16 + col;
  int pv = min(p, DD - 1);
  int py = pv / D, px = pv - py * D;
  const ushort_t* xb = xt + ((size_t)(pixb + n * PDD + (py + 1) * Dp + (px + 1))) * 64 + quad * 8;

  float4v Dk = {0.f, 0.f, 0.f, 0.f};
  float4v Dq = {0.f, 0.f, 0.f, 0.f};
  float4v Dv0 = {0.f, 0.f, 0.f, 0.f};
  float4v Dv1 = {0.f, 0.f, 0.f, 0.f};

#pragma unroll
  for (int dy = -1; dy <= 1; dy++) {
#pragma unroll
    for (int dx = -1; dx <= 1; dx++) {
      int tap = (dy + 1) * 3 + (dx + 1);
      const ushort_t* ab = xb + (dy * Dp + dx) * 64;
#pragma unroll
      for (int half = 0; half < 2; half++) {
        short8 A = *(const short8*)(ab + half * 32);
        int f = (tap * 2 + half) * 2 + crt;
        short8 Bk = *(const short8*)(wpk + (size_t)f * 512 + lane * 8);
        Dk = __builtin_amdgcn_mfma_f32_16x16x32_bf16(A, Bk, Dk, 0, 0, 0);
        if (lvl0) {
          short8 Bq = *(const short8*)(wpq + (size_t)f * 512 + lane * 8);
          Dq = __builtin_amdgcn_mfma_f32_16x16x32_bf16(A, Bq, Dq, 0, 0, 0);
        }
        if (tap == 4) {
          short8 Bv0 = *(const short8*)(wpv + (size_t)(half * 4 + crt * 2) * 512 + lane * 8);
          short8 Bv1 = *(const short8*)(wpv + (size_t)(half * 4 + crt * 2 + 1) * 512 + lane * 8);
          Dv0 = __builtin_amdgcn_mfma_f32_16x16x32_bf16(A, Bv0, Dv0, 0, 0, 0);
          Dv1 = __builtin_amdgcn_mfma_f32_16x16x32_bf16(A, Bv1, Dv1, 0, 0, 0);
        }
      }
    }
  }

  float biask = bm[crt * 16 + col];
  float biasq = bb[crt * 16 + col];
  float biasv0 = ba[crt * 32 + col];
  float biasv1 = ba[crt * 32 + 16 + col];
  int prow = tloc * 16 + quad * 4;
#pragma unroll
  for (int r = 0; r < 4; r++) {
    if (prow + r < DD) {
      int l = lb + prow + r;
      keybf[(size_t)(n * LTOT + l) * 32 + crt * 16 + col] = f2bf(Dk[r] + biask);
      if (lvl0) mbbf[(size_t)(n * HW + l) * 32 + crt * 16 + col] = f2bf((Dq[r] + biasq) * LOG2E);
      rawtbf[(size_t)(n * 64 + crt * 32 + col) * LPAD + l] = f2bf(Dv0[r] + biasv0);
      rawtbf[(size_t)(n * 64 + crt * 32 + 16 + col) * LPAD + l] = f2bf(Dv1[r] + biasv1);
    }
  }
}

// ---------------- MFMA flash attention v2 ----------------
// grid (18 q-tiles of 128, 4 n, NSEG). Block 256 = 4 waves; wave owns 32 q.
// S^T = mfma(K,Q) puts l in the register dim -> P stored [q][l] with b64
// writes, read back as b128 A-frags for PV. K frags direct from global
// (L1/L2); V double-buffered in LDS (reg prefetch); one barrier per chunk.
__global__ __launch_bounds__(256, 4) void k_attn(const ushort_t* __restrict__ mb,
    const ushort_t* __restrict__ keyb, const ushort_t* __restrict__ rawt,
    float* __restrict__ Yp, float* __restrict__ lp) {
  __shared__ __align__(16) ushort_t VsF[2][4096];
  __shared__ __align__(16) ushort_t Pq[4][32 * 72];

  int t = threadIdx.x;
  int n = blockIdx.y, seg = blockIdx.z;
  int lane = t & 63, wv = t >> 6;
  int col = lane & 15, quad = lane >> 4;
  int qb = blockIdx.x * 128 + wv * 32;
  int l_begin = seg * SEG;
  int l_end = min(l_begin + SEG, LTOT);
  int nfull = (l_end - l_begin) >> 6;
  int rem = (l_end - l_begin) & 63;
  int nch = nfull + (rem ? 1 : 0);

  const ushort_t* keyn = keyb + (size_t)n * LTOT * CR;
  const ushort_t* rawn = rawt + (size_t)n * C * LPAD;

  short8 qA0 = *(const short8*)(mb + ((size_t)(n * HW + qb + col)) * CR + quad * 8);
  short8 qA1 = *(const short8*)(mb + ((size_t)(n * HW + qb + 16 + col)) * CR + quad * 8);

  // V staging source offset (kt=0 for vec0, kt=1 for vec1; same ct,g,cc)
  int ct0 = (t >> 6) & 3, g0 = (t >> 4) & 3, cc0 = t & 15;
  size_t so0 = (size_t)(ct0 * 16 + cc0) * LPAD + g0 * 8;

  float4v Y0[4], Y1[4];
#pragma unroll
  for (int ct = 0; ct < 4; ct++)
#pragma unroll
    for (int r = 0; r < 4; r++) { Y0[ct][r] = 0.f; Y1[ct][r] = 0.f; }
  float ls0 = 0.f, ls1 = 0.f;
  const float4v zero4 = {0.f, 0.f, 0.f, 0.f};
  ushort_t* Pw = Pq[wv];

  uint4 va = *(const uint4*)(rawn + so0 + l_begin);
  uint4 vb = *(const uint4*)(rawn + so0 + 32 + l_begin);
  int buf = 0;

  for (int ch = 0; ch < nch; ++ch) {
    int l0 = l_begin + ch * 64;
    *(uint4*)&VsF[buf][t * 8] = va;
    *(uint4*)&VsF[buf][(t + 256) * 8] = vb;
    if (ch + 1 < nch) {
      int ln = l0 + 64;
      va = *(const uint4*)(rawn + so0 + ln);
      vb = *(const uint4*)(rawn + so0 + 32 + ln);
    }
    __syncthreads();

    bool tail = (rem != 0) && (ch == nfull);
    // ---- S^T = K·Q^T, p = exp2, write P[q][l] (b64), accumulate denom ----
#pragma unroll
    for (int tt = 0; tt < 4; tt++) {
      short8 kf = *(const short8*)(keyn + (size_t)(l0 + tt * 16 + col) * CR + quad * 8);
      float4v S0 = __builtin_amdgcn_mfma_f32_16x16x32_bf16(kf, qA0, zero4, 0, 0, 0);
      float4v S1 = __builtin_amdgcn_mfma_f32_16x16x32_bf16(kf, qA1, zero4, 0, 0, 0);
      int lbase = tt * 16 + quad * 4;   // l within chunk for r=0
      float p0[4], p1[4];
#pragma unroll
      for (int r = 0; r < 4; r++) {
        bool ok = !tail || (lbase + r < rem);
        float a = __builtin_amdgcn_exp2f(S0[r]);
        float b = __builtin_amdgcn_exp2f(S1[r]);
        p0[r] = ok ? a : 0.f;
        p1[r] = ok ? b : 0.f;
        ls0 += p0[r];
        ls1 += p1[r];
      }
      union { float f; unsigned u; } c0, c1;
      uint2 w;
      c0.f = p0[0]; c1.f = p0[1];
      w.x = ((c0.u + 0x8000u) >> 16) | ((c1.u + 0x8000u) & 0xFFFF0000u);
      c0.f = p0[2]; c1.f = p0[3];
      w.y = ((c0.u + 0x8000u) >> 16) | ((c1.u + 0x8000u) & 0xFFFF0000u);
      *(uint2*)&Pw[col * 72 + lbase] = w;
      c0.f = p1[0]; c1.f = p1[1];
      w.x = ((c0.u + 0x8000u) >> 16) | ((c1.u + 0x8000u) & 0xFFFF0000u);
      c0.f = p1[2]; c1.f = p1[3];
      w.y = ((c0.u + 0x8000u) >> 16) | ((c1.u + 0x8000u) & 0xFFFF0000u);
      *(uint2*)&Pw[(16 + col) * 72 + lbase] = w;
    }

    // ---- PV: Y += P·V ----
#pragma unroll
    for (int kt = 0; kt < 2; kt++) {
      short8 a0 = *(const short8*)&Pw[col * 72 + kt * 32 + quad * 8];
      short8 a1 = *(const short8*)&Pw[(16 + col) * 72 + kt * 32 + quad * 8];
#pragma unroll
      for (int ct = 0; ct < 4; ct++) {
        short8 bV = *(const short8*)&VsF[buf][(((kt << 2) | ct) * 64 + lane) * 8];
        Y0[ct] = __builtin_amdgcn_mfma_f32_16x16x32_bf16(a0, bV, Y0[ct], 0, 0, 0);
        Y1[ct] = __builtin_amdgcn_mfma_f32_16x16x32_bf16(a1, bV, Y1[ct], 0, 0, 0);
      }
    }
    buf ^= 1;
  }

  // denominator: sum the quad-partials (each lane holds partial for q=col)
  ls0 += __shfl_xor(ls0, 16); ls0 += __shfl_xor(ls0, 32);
  ls1 += __shfl_xor(ls1, 16); ls1 += __shfl_xor(ls1, 32);

  float* yo = Yp + ((size_t)(seg * NB + n) * HW + qb) * C;
#pragma unroll
  for (int ct = 0; ct < 4; ct++)
#pragma unroll
    for (int r = 0; r < 4; r++) {
      yo[(quad * 4 + r) * C + ct * 16 + col] = Y0[ct][r];
      yo[(16 + quad * 4 + r) * C + ct * 16 + col] = Y1[ct][r];
    }
  if (quad == 0) {
    int base = (seg * NB + n) * HW + qb;
    lp[base + col] = ls0;
    lp[base + 16 + col] = ls1;
  }
}

// ---------------- combine segment partials + residual ----------------
__global__ void k_combine(const float* __restrict__ x, const float* __restrict__ ws,
                          float* __restrict__ out) {
  int tid = blockIdx.x * 256 + threadIdx.x;
  int c = tid & 63;
  int t2 = tid >> 6;
  int q = t2 % HW;
  int n = t2 / HW;
  const float* Yv = ws + YP_F;
  const float* lpv = ws + LP_F;
  int i0 = n * HW + q;
  float den = 0.f, num = 0.f;
#pragma unroll
  for (int s = 0; s < NSEG; s++) {
    int idx = s * NB * HW + i0;
    den += lpv[idx];
    num += Yv[(size_t)idx * C + c];
  }
  int oi = (n * C + c) * HW + q;
  out[oi] = num / den + x[oi];
}

extern "C" void kernel_launch(void* const* d_in, const int* in_sizes, int n_in,
                              void* d_out, int out_size, void* d_ws, size_t ws_size,
                              hipStream_t stream) {
  const float* x  = (const float*)d_in[0];
  const float* wb = (const float*)d_in[1];
  const float* bb = (const float*)d_in[2];
  const float* wm = (const float*)d_in[3];
  const float* bm = (const float*)d_in[4];
  const float* wa = (const float*)d_in[5];
  const float* ba = (const float*)d_in[6];
  float* out = (float*)d_out;
  float* ws = (float*)d_ws;
  ushort_t* xt     = (ushort_t*)ws;
  ushort_t* mbbf   = (ushort_t*)(ws + MBBF_F);
  ushort_t* keybf  = (ushort_t*)(ws + KEYBF_F);
  ushort_t* rawtbf = (ushort_t*)(ws + RAWTBF_F);
  ushort_t* wpk    = (ushort_t*)(ws + WPK_F);
  ushort_t* wpq    = (ushort_t*)(ws + WPQ_F);
  ushort_t* wpv    = (ushort_t*)(ws + WPV_F);

  k_zero<<<1032, 256, 0, stream>>>(xt);
  k_pad0<<<dim3(48, 4), 256, 0, stream>>>(x, xt);
  k_resize<<<5166, 256, 0, stream>>>(x, xt);
  k_wpack<<<20, 256, 0, stream>>>(wm, wb, wa, wpk, wpq, wpv);
  k_conv<<<dim3(235, 4), 256, 0, stream>>>(xt, wpk, wpq, wpv, bm, bb, ba,
                                           keybf, mbbf, rawtbf);
  k_attn<<<dim3(18, 4, NSEG), 256, 0, stream>>>(mbbf, keybf, rawtbf,
      ws + YP_F, ws + LP_F);
  k_combine<<<2304, 256, 0, stream>>>(x, ws, out);
}